// Round 1
// baseline (339.519 us; speedup 1.0000x reference)
//
#include <hip/hip_runtime.h>
#include <cstdint>
#include <math.h>

typedef unsigned short u16;
typedef __attribute__((ext_vector_type(8))) short bf16x8;  // 8 bf16 (4 VGPRs)
typedef __attribute__((ext_vector_type(4))) float f32x4;   // MFMA acc

#define DEVI __device__ __forceinline__

DEVI u16 f2bf(float f) {
  union { float f; uint32_t u; } v; v.f = f;
  return (u16)((v.u + 0x7FFFu + ((v.u >> 16) & 1u)) >> 16);  // RNE
}
DEVI float bf2f(u16 h) {
  union { uint32_t u; float f; } v; v.u = ((uint32_t)h) << 16;
  return v.f;
}

// async global->LDS, 16B per lane. LDS dst = wave-uniform base + lane*16.
DEVI void gload16(const void* g, void* l) {
  __builtin_amdgcn_global_load_lds(
      (const __attribute__((address_space(1))) void*)g,
      (__attribute__((address_space(3))) void*)l, 16, 0, 0);
}

// tanh-form GELU: u*(1 - 1/(1+e^{2*0.79788456*(u+0.044715u^3)}))
DEVI float gelu_fast(float u) {
  float u2 = u * u;
  float t = __builtin_fmaf(0.044715f * u2, u, u);
  float e = __expf(1.5957691216057308f * t);
  float r = __builtin_amdgcn_rcpf(1.0f + e);
  return u - u * r;
}

// ---------------------------------------------------------------------------
// fp32 W[K][N] -> bf16 Wt[N][K] transpose-convert, one 64x64 tile via LDS
// ---------------------------------------------------------------------------
DEVI void tcvt_body(const float* __restrict__ W, u16* __restrict__ Wt,
                    int Kd, int N, int n0, int k0, float* t) {
  const int r = threadIdx.x >> 4, c4 = (threadIdx.x & 15) * 4;
#pragma unroll
  for (int p = 0; p < 4; ++p) {
    int row = p * 16 + r;
    float4 f = *(const float4*)(W + (size_t)(k0 + row) * N + n0 + c4);
    *(float4*)&t[row * 68 + c4] = f;
  }
  __syncthreads();
#pragma unroll
  for (int p = 0; p < 4; ++p) {
    int n = p * 16 + r;
    float v0 = t[(c4 + 0) * 68 + n];
    float v1 = t[(c4 + 1) * 68 + n];
    float v2 = t[(c4 + 2) * 68 + n];
    float v3 = t[(c4 + 3) * 68 + n];
    uint32_t lo = (uint32_t)f2bf(v0) | ((uint32_t)f2bf(v1) << 16);
    uint32_t hi = (uint32_t)f2bf(v2) | ((uint32_t)f2bf(v3) << 16);
    *(uint2*)(Wt + (size_t)(n0 + n) * Kd + k0 + c4) = make_uint2(lo, hi);
  }
}

// ---------------------------------------------------------------------------
// Fused prep: all weight transpose-converts + x convert + bias concat.
// ---------------------------------------------------------------------------
__global__ __launch_bounds__(256)
void prep_kernel(const float* __restrict__ Wq, const float* __restrict__ Wk,
                 const float* __restrict__ Wv, const float* __restrict__ Wo,
                 const float* __restrict__ W1, const float* __restrict__ W2,
                 const float* __restrict__ x, const float* __restrict__ bq,
                 const float* __restrict__ bk, const float* __restrict__ bv,
                 u16* __restrict__ WqkvT, u16* __restrict__ WoT,
                 u16* __restrict__ W1T, u16* __restrict__ W2T,
                 u16* __restrict__ xb, float* __restrict__ bqkv)
{
  __shared__ float t[64 * 68];
  const int b = blockIdx.x;
  if (b < 1024) {
    int wsel = b >> 8, tt = b & 255;
    const float* W = (wsel == 0) ? Wq : (wsel == 1) ? Wk : (wsel == 2) ? Wv : Wo;
    u16* dst = (wsel == 3) ? WoT : WqkvT + (size_t)wsel * 1024 * 1024;
    tcvt_body(W, dst, 1024, 1024, (tt & 15) * 64, (tt >> 4) * 64, t);
  } else if (b < 2048) {
    int tt = b - 1024;
    tcvt_body(W1, W1T, 1024, 4096, (tt & 63) * 64, (tt >> 6) * 64, t);
  } else if (b < 3072) {
    int tt = b - 2048;
    tcvt_body(W2, W2T, 4096, 1024, (tt & 15) * 64, (tt >> 4) * 64, t);
  } else if (b < 7168) {
    int i = ((b - 3072) * 256 + threadIdx.x) * 4;
    float4 f = *(const float4*)(x + i);
    uint32_t lo = (uint32_t)f2bf(f.x) | ((uint32_t)f2bf(f.y) << 16);
    uint32_t hi = (uint32_t)f2bf(f.z) | ((uint32_t)f2bf(f.w) << 16);
    *(uint2*)(xb + i) = make_uint2(lo, hi);
  } else {
    int i = (b - 7168) * 256 + threadIdx.x;  // 0..3071
    const float* s = (i < 1024) ? bq : ((i < 2048) ? bk : bv);
    bqkv[i] = s[i & 1023];
  }
}

// ---------------------------------------------------------------------------
// Legacy GEMM: 128x128 tile, BK=64, 256 thr. Used for G2/G4 (N=1024 shapes).
// ---------------------------------------------------------------------------
template<int MODE>
__global__ __launch_bounds__(256, 4)
void gemm_kernel(const u16* __restrict__ A, const u16* __restrict__ Bt,
                 const float* __restrict__ bias, void* __restrict__ C0,
                 void* __restrict__ C1, int N, int Kfull, int Kpart)
{
  __shared__ u16 As0[128 * 32], As1[128 * 32];
  __shared__ u16 Bs0[128 * 32], Bs1[128 * 32];
  const int tid = threadIdx.x;
  const int nbx = gridDim.x, nby = gridDim.y;
  int lin = blockIdx.y * nbx + blockIdx.x;
  int band = lin / (8 * nbx);
  int rem = lin - band * (8 * nbx);
  int gsz = min(nby - band * 8, 8);
  const int m0 = (band * 8 + rem % gsz) * 128;
  const int n0 = (rem / gsz) * 128;
  const int kbase = (MODE == 2) ? (int)blockIdx.z * Kpart : 0;
  const int w = tid >> 6, lane = tid & 63;
  const int wm = (w >> 1) * 64, wn = (w & 1) * 64;
  const int mr = lane & 15, ko = (lane >> 4) * 8;
  const int rq = (lane >> 4) * 4;
  const int w32 = w * 32;

  f32x4 acc[4][4];
#pragma unroll
  for (int i = 0; i < 4; ++i)
#pragma unroll
    for (int j = 0; j < 4; ++j) {
      f32x4 z = {0.f, 0.f, 0.f, 0.f};
      acc[i][j] = z;
    }

  const int lr = lane >> 2, lk = (lane & 3) * 8;
  const u16* aG = A  + (size_t)(m0 + w32 + lr) * Kfull + kbase + lk;
  const u16* bG = Bt + (size_t)(n0 + w32 + lr) * Kfull + kbase + lk;
  u16* aD00 = &As0[(w32 +  0) * 32];
  u16* aD01 = &As0[(w32 + 16) * 32];
  u16* aD10 = &As1[(w32 +  0) * 32];
  u16* aD11 = &As1[(w32 + 16) * 32];
  u16* bD00 = &Bs0[(w32 +  0) * 32];
  u16* bD01 = &Bs0[(w32 + 16) * 32];
  u16* bD10 = &Bs1[(w32 +  0) * 32];
  u16* bD11 = &Bs1[(w32 + 16) * 32];
  const size_t row16 = (size_t)16 * Kfull;

  for (int k0 = 0; k0 < Kpart; k0 += 64) {
    gload16(aG + k0,              aD00);
    gload16(aG + row16 + k0,      aD01);
    gload16(aG + k0 + 32,         aD10);
    gload16(aG + row16 + k0 + 32, aD11);
    gload16(bG + k0,              bD00);
    gload16(bG + row16 + k0,      bD01);
    gload16(bG + k0 + 32,         bD10);
    gload16(bG + row16 + k0 + 32, bD11);
    __syncthreads();
#pragma unroll
    for (int s = 0; s < 2; ++s) {
      const u16* Ap = s ? As1 : As0;
      const u16* Bp = s ? Bs1 : Bs0;
      bf16x8 af[4], bf[4];
#pragma unroll
      for (int i = 0; i < 4; ++i)
        af[i] = *(const bf16x8*)&Ap[(wm + i * 16 + mr) * 32 + ko];
#pragma unroll
      for (int j = 0; j < 4; ++j)
        bf[j] = *(const bf16x8*)&Bp[(wn + j * 16 + mr) * 32 + ko];
#pragma unroll
      for (int i = 0; i < 4; ++i)
#pragma unroll
        for (int j = 0; j < 4; ++j)
          acc[i][j] = __builtin_amdgcn_mfma_f32_16x16x32_bf16(bf[j], af[i], acc[i][j], 0, 0, 0);
    }
    __syncthreads();
  }

  {
    const bool part1 = (MODE == 2) && (blockIdx.z == 1);
#pragma unroll
    for (int i = 0; i < 4; ++i) {
      size_t mrow = (size_t)(m0 + wm + i * 16 + mr) * N;
#pragma unroll
      for (int j = 0; j < 4; ++j) {
        int nb = n0 + wn + j * 16 + rq;
        float v0 = acc[i][j][0], v1 = acc[i][j][1];
        float v2 = acc[i][j][2], v3 = acc[i][j][3];
        if (!part1) {
          float4 b4 = *(const float4*)&bias[nb];
          v0 += b4.x; v1 += b4.y; v2 += b4.z; v3 += b4.w;
        }
        if (MODE == 1) {
          v0 = gelu_fast(v0); v1 = gelu_fast(v1);
          v2 = gelu_fast(v2); v3 = gelu_fast(v3);
        }
        uint32_t lo = (uint32_t)f2bf(v0) | ((uint32_t)f2bf(v1) << 16);
        uint32_t hi = (uint32_t)f2bf(v2) | ((uint32_t)f2bf(v3) << 16);
        u16* dst = part1 ? (u16*)C1 : (u16*)C0;
        *(uint2*)(dst + mrow + nb) = make_uint2(lo, hi);
      }
    }
  }
}

// ---------------------------------------------------------------------------
// 256x256 8-phase GEMM (T2 swizzle + T3/T4 counted-vmcnt + T5 setprio).
// 512 thr = 8 waves (2m x 4n); per-wave C = 128x64 (acc[8][4] f32x4).
// BK=64; LDS = 2 buf x 2 half x [128 rows x 64 u16] per operand = 128 KiB.
// Per K-tile: 4 phases = C-quadrants (A0B0),(A0B1),(A1B1),(A1B0); each phase:
//   stage 1 half-tile of tile t+1 into buf (t+1)&1  (2 x global_load_lds 16B)
//   12 ds_read_b128 (XOR-swizzled cols: byte ^= (row&7)<<4; global src
//     pre-swizzled with the same involution so gload_lds stays linear)
//   s_barrier; setprio(1); 16 MFMA; setprio(0); s_waitcnt vmcnt(4); s_barrier
// Invariant (stage order A0,B0,B1,A1): vmcnt(4) at each phase end leaves the
// last 2 staged halves in flight and guarantees each half lands >=1 phase
// before its first read. Stages never touch the buffer being read.
// Last tile: no stages; waits 2 -> 0 -> none -> none.
// MODE 0: fused QKV epilogue (n0<2048 -> QKb packed; else V -> Vt transposed)
// MODE 1: bias + fast GELU -> bf16.
// ---------------------------------------------------------------------------
#define VMW4 asm volatile("s_waitcnt vmcnt(4)" ::: "memory")
#define VMW2 asm volatile("s_waitcnt vmcnt(2)" ::: "memory")
#define VMW0 asm volatile("s_waitcnt vmcnt(0)" ::: "memory")
#define VMWN

DEVI void stage_half(const u16* __restrict__ G, int row0, int Kfull, int tk,
                     u16* lds_half, int w, int srow, int scol) {
  const u16* s = G + (size_t)(row0 + w * 8 + srow) * Kfull + tk + scol;
  u16* d = lds_half + w * 512;                 // wave-uniform dest
  gload16(s, d);                               // rows [0,64) of the half
  gload16(s + ((size_t)Kfull << 6), d + 4096); // rows [64,128)
}

#define PH(MH, NH, WAIT) do {                                                 \
    const u16* Ab_ = &As[(cur * 2 + (MH)) * 8192];                            \
    const u16* Bb_ = &Bs[(cur * 2 + (NH)) * 8192];                            \
    bf16x8 a0_[4], a1_[4], b0_[2], b1_[2];                                    \
    _Pragma("unroll")                                                         \
    for (int i_ = 0; i_ < 4; ++i_) {                                          \
      const u16* p_ = Ab_ + (wm * 64 + i_ * 16 + mr) * 64;                    \
      a0_[i_] = *(const bf16x8*)(p_ + c0);                                    \
      a1_[i_] = *(const bf16x8*)(p_ + c1);                                    \
    }                                                                         \
    _Pragma("unroll")                                                         \
    for (int j_ = 0; j_ < 2; ++j_) {                                          \
      const u16* p_ = Bb_ + (wn * 32 + j_ * 16 + mr) * 64;                    \
      b0_[j_] = *(const bf16x8*)(p_ + c0);                                    \
      b1_[j_] = *(const bf16x8*)(p_ + c1);                                    \
    }                                                                         \
    __builtin_amdgcn_s_barrier();                                             \
    __builtin_amdgcn_s_setprio(1);                                            \
    _Pragma("unroll")                                                         \
    for (int i_ = 0; i_ < 4; ++i_)                                            \
      _Pragma("unroll")                                                       \
      for (int j_ = 0; j_ < 2; ++j_) {                                        \
        acc[(MH)*4+i_][(NH)*2+j_] = __builtin_amdgcn_mfma_f32_16x16x32_bf16(  \
            b0_[j_], a0_[i_], acc[(MH)*4+i_][(NH)*2+j_], 0, 0, 0);            \
        acc[(MH)*4+i_][(NH)*2+j_] = __builtin_amdgcn_mfma_f32_16x16x32_bf16(  \
            b1_[j_], a1_[i_], acc[(MH)*4+i_][(NH)*2+j_], 0, 0, 0);            \
      }                                                                       \
    __builtin_amdgcn_s_setprio(0);                                            \
    WAIT;                                                                     \
    __builtin_amdgcn_s_barrier();                                             \
  } while (0)

template<int MODE>
__global__ __launch_bounds__(512, 2)
void gemm256_kernel(const u16* __restrict__ A, const u16* __restrict__ Bt,
                    const float* __restrict__ bias, void* __restrict__ C0,
                    void* __restrict__ C1, int N, int Kfull, int NBN)
{
  __shared__ u16 As[32768];   // 2 buf x 2 half x 128x64
  __shared__ u16 Bs[32768];
  const int tid = threadIdx.x;
  const int w = tid >> 6, lane = tid & 63;
  const int wm = w >> 2, wn = w & 3;           // 2 x 4 waves
  const int mr = lane & 15;
  const int rq = (lane >> 4) * 4;

  // XCD-bijective swizzle (gridDim.x % 8 == 0): same-mt runs share an XCD L2.
  const int lin = blockIdx.x;
  const int q = gridDim.x >> 3;
  const int wg = (lin & 7) * q + (lin >> 3);
  const int mt = wg / NBN, nt = wg - mt * NBN;
  const int m0 = mt * 256, n0 = nt * 256;

  // stage-side mapping (linear LDS dest; inverse-swizzled global source)
  const int srow = lane >> 3;                       // 0..7
  const int scol = ((lane & 7) ^ srow) << 3;        // u16 col within 64
  // read-side swizzled k-columns (u16): byte = (ksub*64 + (lane>>4)*16) ^ ((mr&7)<<4)
  const int bl = (lane >> 4) << 4;
  const int sw = (mr & 7) << 4;
  const int c0 = (bl ^ sw) >> 1;
  const int c1 = ((64 + bl) ^ sw) >> 1;

  f32x4 acc[8][4];
#pragma unroll
  for (int i = 0; i < 8; ++i)
#pragma unroll
    for (int j = 0; j < 4; ++j) {
      f32x4 z = {0.f, 0.f, 0.f, 0.f};
      acc[i][j] = z;
    }

  const int NT = Kfull >> 6;

  // prologue: tile 0, order A0,B0,B1,A1 -> vmcnt(4) = {A0,B0} landed
  stage_half(A,  m0 + 0,   Kfull, 0, &As[0],    w, srow, scol);
  stage_half(Bt, n0 + 0,   Kfull, 0, &Bs[0],    w, srow, scol);
  stage_half(Bt, n0 + 128, Kfull, 0, &Bs[8192], w, srow, scol);
  stage_half(A,  m0 + 128, Kfull, 0, &As[8192], w, srow, scol);
  VMW4;
  __builtin_amdgcn_s_barrier();

  int t = 0;
  for (; t < NT - 1; ++t) {
    const int cur = t & 1, nxt = cur ^ 1, k1 = (t + 1) * 64;
    stage_half(A,  m0 + 0,   Kfull, k1, &As[(nxt*2+0)*8192], w, srow, scol);
    PH(0, 0, VMW4);
    stage_half(Bt, n0 + 0,   Kfull, k1, &Bs[(nxt*2+0)*8192], w, srow, scol);
    PH(0, 1, VMW4);
    stage_half(Bt, n0 + 128, Kfull, k1, &Bs[(nxt*2+1)*8192], w, srow, scol);
    PH(1, 1, VMW4);
    stage_half(A,  m0 + 128, Kfull, k1, &As[(nxt*2+1)*8192], w, srow, scol);
    PH(1, 0, VMW4);
  }
  {
    const int cur = t & 1;
    PH(0, 0, VMW2);
    PH(0, 1, VMW0);
    PH(1, 1, VMWN);
    PH(1, 0, VMWN);
  }

  // epilogue: m = m0 + (mi>>2)*128 + wm*64 + (mi&3)*16 + mr
  //           n = n0 + (ni>>1)*128 + wn*32 + (ni&1)*16 + rq + r
  if (MODE == 0) {
    if (n0 < 2048) {  // Q,K -> QKb [4096][2048], packed along n
#pragma unroll
      for (int mi = 0; mi < 8; ++mi) {
        int mg = m0 + (mi >> 2) * 128 + wm * 64 + (mi & 3) * 16 + mr;
        size_t mrow = (size_t)mg * 2048;
#pragma unroll
        for (int ni = 0; ni < 4; ++ni) {
          int ng = n0 + (ni >> 1) * 128 + wn * 32 + (ni & 1) * 16 + rq;
          float4 b4 = *(const float4*)&bias[ng];
          f32x4 a = acc[mi][ni];
          uint32_t lo = (uint32_t)f2bf(a[0] + b4.x) | ((uint32_t)f2bf(a[1] + b4.y) << 16);
          uint32_t hi = (uint32_t)f2bf(a[2] + b4.z) | ((uint32_t)f2bf(a[3] + b4.w) << 16);
          *(uint2*)((u16*)C0 + mrow + ng) = make_uint2(lo, hi);
        }
      }
    } else {          // V -> Vt [1024][4096] transposed
#pragma unroll
      for (int mi = 0; mi < 8; ++mi) {
        int mg = m0 + (mi >> 2) * 128 + wm * 64 + (mi & 3) * 16 + mr;
#pragma unroll
        for (int ni = 0; ni < 4; ++ni) {
          int ng = n0 + (ni >> 1) * 128 + wn * 32 + (ni & 1) * 16 + rq;
          float4 b4 = *(const float4*)&bias[ng];
          f32x4 a = acc[mi][ni];
          int d = ng - 2048;
          ((u16*)C1)[(size_t)(d + 0) * 4096 + mg] = f2bf(a[0] + b4.x);
          ((u16*)C1)[(size_t)(d + 1) * 4096 + mg] = f2bf(a[1] + b4.y);
          ((u16*)C1)[(size_t)(d + 2) * 4096 + mg] = f2bf(a[2] + b4.z);
          ((u16*)C1)[(size_t)(d + 3) * 4096 + mg] = f2bf(a[3] + b4.w);
        }
      }
    }
  } else {            // MODE 1: bias + GELU -> bf16
#pragma unroll
    for (int mi = 0; mi < 8; ++mi) {
      int mg = m0 + (mi >> 2) * 128 + wm * 64 + (mi & 3) * 16 + mr;
      size_t mrow = (size_t)mg * N;
#pragma unroll
      for (int ni = 0; ni < 4; ++ni) {
        int ng = n0 + (ni >> 1) * 128 + wn * 32 + (ni & 1) * 16 + rq;
        float4 b4 = *(const float4*)&bias[ng];
        f32x4 a = acc[mi][ni];
        float v0 = gelu_fast(a[0] + b4.x), v1 = gelu_fast(a[1] + b4.y);
        float v2 = gelu_fast(a[2] + b4.z), v3 = gelu_fast(a[3] + b4.w);
        uint32_t lo = (uint32_t)f2bf(v0) | ((uint32_t)f2bf(v1) << 16);
        uint32_t hi = (uint32_t)f2bf(v2) | ((uint32_t)f2bf(v3) << 16);
        *(uint2*)((u16*)C0 + mrow + ng) = make_uint2(lo, hi);
      }
    }
  }
}

// ---------------------------------------------------------------------------
// Banded MFMA flash attention, simplified softmax. QK^T swapped -> S[t][q]:
// lane owns ONE q -> packed b64 P-writes, scalar l. PV swapped -> O[d][q].
// ---------------------------------------------------------------------------
__global__ __launch_bounds__(256)
void attn_kernel(const u16* __restrict__ QKb, const u16* __restrict__ Vt,
                 u16* __restrict__ ctx)
{
  const int KS = 2048, HD = 1024;
  __shared__ u16 Qs[64 * 80];
  __shared__ u16 Ks[64 * 80];
  __shared__ u16 Vts[64 * 72];   // [d][t]
  __shared__ u16 Ps[64 * 72];    // [q][t]

  const int qt = blockIdx.x, hh = blockIdx.y, bb = blockIdx.z;
  const int s0 = qt * 64;
  const int tid = threadIdx.x, w = tid >> 6, lane = tid & 63;
  const int mr = lane & 15, ko = (lane >> 4) * 8, rq = (lane >> 4) * 4;
  const int sr = tid >> 3, sc = (tid & 7) * 8;
  const int vrow = tid >> 2, vtc = (tid & 3) * 16;
  const float qsc = 0.022097086912079608f;  // 1/sqrt(2048)
  const int qg = s0 + w * 16 + mr;          // this lane's query row

#pragma unroll
  for (int p = 0; p < 2; ++p) {
    int row = p * 32 + sr;
    uint4 u = *(const uint4*)(QKb + (size_t)(bb * KS + s0 + row) * 2048 + hh * 64 + sc);
    *(uint4*)&Qs[row * 80 + sc] = u;
  }

  f32x4 accO[4];
#pragma unroll
  for (int j = 0; j < 4; ++j) { f32x4 z = {0.f,0.f,0.f,0.f}; accO[j] = z; }
  float lsum = 0.f;

  for (int c = 0; c < 9; ++c) {
    int tb = s0 - 256 + c * 64;
    if (tb < 0 || tb >= KS) continue;
    __syncthreads();
#pragma unroll
    for (int p = 0; p < 2; ++p) {
      int row = p * 32 + sr;
      uint4 uk = *(const uint4*)(QKb + (size_t)(bb * KS + tb + row) * 2048 + 1024 + hh * 64 + sc);
      *(uint4*)&Ks[row * 80 + sc] = uk;
    }
    {
      const u16* vsrc = Vt + (size_t)(hh * 64 + vrow) * 4096 + bb * KS + tb + vtc;
      *(uint4*)&Vts[vrow * 72 + vtc]     = *(const uint4*)vsrc;
      *(uint4*)&Vts[vrow * 72 + vtc + 8] = *(const uint4*)(vsrc + 8);
    }
    __syncthreads();

    f32x4 sacc[4];
#pragma unroll
    for (int j = 0; j < 4; ++j) { f32x4 z = {0.f,0.f,0.f,0.f}; sacc[j] = z; }
#pragma unroll
    for (int s = 0; s < 2; ++s) {
      bf16x8 aq = *(const bf16x8*)&Qs[(w * 16 + mr) * 80 + s * 32 + ko];
#pragma unroll
      for (int j = 0; j < 4; ++j) {
        bf16x8 bk = *(const bf16x8*)&Ks[(j * 16 + mr) * 80 + s * 32 + ko];
        sacc[j] = __builtin_amdgcn_mfma_f32_16x16x32_bf16(bk, aq, sacc[j], 0, 0, 0);
      }
    }

#pragma unroll
    for (int j = 0; j < 4; ++j) {
      int tgb = tb + j * 16 + rq;
      float p0, p1, p2, p3;
      {
        int d0 = qg - tgb;
        float s_ = sacc[j][0] * qsc;
        p0 = (d0 > 256 || d0 < -256) ? 0.f : __expf(s_);
        int d1 = d0 - 1; s_ = sacc[j][1] * qsc;
        p1 = (d1 > 256 || d1 < -256) ? 0.f : __expf(s_);
        int d2 = d0 - 2; s_ = sacc[j][2] * qsc;
        p2 = (d2 > 256 || d2 < -256) ? 0.f : __expf(s_);
        int d3 = d0 - 3; s_ = sacc[j][3] * qsc;
        p3 = (d3 > 256 || d3 < -256) ? 0.f : __expf(s_);
      }
      lsum += p0 + p1 + p2 + p3;
      uint32_t lo = (uint32_t)f2bf(p0) | ((uint32_t)f2bf(p1) << 16);
      uint32_t hi = (uint32_t)f2bf(p2) | ((uint32_t)f2bf(p3) << 16);
      *(uint2*)&Ps[(w * 16 + mr) * 72 + j * 16 + rq] = make_uint2(lo, hi);
    }
#pragma unroll
    for (int s = 0; s < 2; ++s) {
      bf16x8 ap = *(const bf16x8*)&Ps[(w * 16 + mr) * 72 + s * 32 + ko];
#pragma unroll
      for (int j = 0; j < 4; ++j) {
        bf16x8 bv = *(const bf16x8*)&Vts[(j * 16 + mr) * 72 + s * 32 + ko];
        accO[j] = __builtin_amdgcn_mfma_f32_16x16x32_bf16(bv, ap, accO[j], 0, 0, 0);
      }
    }
  }

  float l = lsum;
  l += __shfl_xor(l, 16, 64);
  l += __shfl_xor(l, 32, 64);
  float inv = 1.f / l;
  size_t base = (size_t)(bb * KS + qg) * HD + hh * 64;
#pragma unroll
  for (int j = 0; j < 4; ++j) {
    uint32_t lo = (uint32_t)f2bf(accO[j][0] * inv) | ((uint32_t)f2bf(accO[j][1] * inv) << 16);
    uint32_t hi = (uint32_t)f2bf(accO[j][2] * inv) | ((uint32_t)f2bf(accO[j][3] * inv) << 16);
    *(uint2*)(ctx + base + j * 16 + rq) = make_uint2(lo, hi);
  }
}

// ---------------------------------------------------------------------------
// LayerNorm(p0 + p1 + res) over D=1024; all inputs bf16.
// ---------------------------------------------------------------------------
DEVI void bfadd4(const u16* p, size_t base, float& v0, float& v1, float& v2, float& v3) {
  uint2 u = *(const uint2*)(p + base);
  v0 += bf2f((u16)(u.x & 0xFFFFu));
  v1 += bf2f((u16)(u.x >> 16));
  v2 += bf2f((u16)(u.y & 0xFFFFu));
  v3 += bf2f((u16)(u.y >> 16));
}

template<int OUT32>
__global__ __launch_bounds__(256)
void ln_kernel(const u16* __restrict__ p0, const u16* __restrict__ p1,
               const u16* __restrict__ res, const float* __restrict__ g,
               const float* __restrict__ be, void* __restrict__ out)
{
  __shared__ float red[8];
  const int row = blockIdx.x, tid = threadIdx.x;
  const int w = tid >> 6, lane = tid & 63;
  size_t base = (size_t)row * 1024 + tid * 4;
  float v0 = 0.f, v1 = 0.f, v2 = 0.f, v3 = 0.f;
  bfadd4(p0, base, v0, v1, v2, v3);
  bfadd4(p1, base, v0, v1, v2, v3);
  bfadd4(res, base, v0, v1, v2, v3);
  float s1 = v0 + v1 + v2 + v3;
  float s2 = v0 * v0 + v1 * v1 + v2 * v2 + v3 * v3;
#pragma unroll
  for (int o = 32; o > 0; o >>= 1) {
    s1 += __shfl_xor(s1, o, 64);
    s2 += __shfl_xor(s2, o, 64);
  }
  if (lane == 0) { red[w] = s1; red[4 + w] = s2; }
  __syncthreads();
  s1 = red[0] + red[1] + red[2] + red[3];
  s2 = red[4] + red[5] + red[6] + red[7];
  float mu = s1 * (1.f / 1024.f);
  float var = s2 * (1.f / 1024.f) - mu * mu;
  float rs = rsqrtf(var + 1e-5f);
  float4 gv = *(const float4*)(g + tid * 4);
  float4 bv = *(const float4*)(be + tid * 4);
  float o0 = (v0 - mu) * rs * gv.x + bv.x;
  float o1 = (v1 - mu) * rs * gv.y + bv.y;
  float o2 = (v2 - mu) * rs * gv.z + bv.z;
  float o3 = (v3 - mu) * rs * gv.w + bv.w;
  if (OUT32) {
    float4 ov; ov.x = o0; ov.y = o1; ov.z = o2; ov.w = o3;
    *(float4*)((float*)out + base) = ov;
  } else {
    uint32_t lo = (uint32_t)f2bf(o0) | ((uint32_t)f2bf(o1) << 16);
    uint32_t hi = (uint32_t)f2bf(o2) | ((uint32_t)f2bf(o3) << 16);
    *(uint2*)((u16*)out + base) = make_uint2(lo, hi);
  }
}

// ---------------------------------------------------------------------------
// ws layout (64 MiB), MiB offsets, lifetime-verified (unchanged):
//  [0,8)   W1T -> Y0b;  [8,16) xb -> Y1b;  [16,24) WqkvT/WoT -> X1b
//  [24,40) QKb -> SA0b/SA1b -> Hb[lo];  [40,48) Vt -> Hb[mid]
//  [48,56) bqkv -> Cb -> Hb[hi];  [56,64) W2T
// ---------------------------------------------------------------------------
extern "C" void kernel_launch(void* const* d_in, const int* in_sizes, int n_in,
                              void* d_out, int out_size, void* d_ws, size_t ws_size,
                              hipStream_t stream)
{
  (void)in_sizes; (void)n_in; (void)out_size; (void)ws_size;
  const float* x   = (const float*)d_in[0];
  const float* Wq  = (const float*)d_in[1];
  const float* bq  = (const float*)d_in[2];
  const float* Wk  = (const float*)d_in[3];
  const float* bk  = (const float*)d_in[4];
  const float* Wv  = (const float*)d_in[5];
  const float* bv  = (const float*)d_in[6];
  const float* Wo  = (const float*)d_in[7];
  const float* bo  = (const float*)d_in[8];
  const float* W1  = (const float*)d_in[9];
  const float* b1  = (const float*)d_in[10];
  const float* W2  = (const float*)d_in[11];
  const float* b2  = (const float*)d_in[12];
  const float* g1  = (const float*)d_in[13];
  const float* be1 = (const float*)d_in[14];
  const float* g2  = (const float*)d_in[15];
  const float* be2 = (const float*)d_in[16];

  char* ws = (char*)d_ws;
  const size_t MB = 1048576;
  u16*   W1T   = (u16*)(ws + 0 * MB);
  u16*   Y0b   = (u16*)(ws + 0 * MB);
  u16*   xb    = (u16*)(ws + 8 * MB);
  u16*   Y1b   = (u16*)(ws + 8 * MB);
  u16*   WqkvT = (u16*)(ws + 16 * MB);
  u16*   X1b   = (u16*)(ws + 16 * MB);
  u16*   WoT   = (u16*)(ws + 22 * MB);
  u16*   QKb   = (u16*)(ws + 24 * MB);
  u16*   SA0b  = (u16*)(ws + 24 * MB);
  u16*   SA1b  = (u16*)(ws + 32 * MB);
  u16*   Hb    = (u16*)(ws + 24 * MB);
  u16*   Vt    = (u16*)(ws + 40 * MB);
  float* bqkv  = (float*)(ws + 48 * MB);
  u16*   Cb    = (u16*)(ws + 48 * MB);
  u16*   W2T   = (u16*)(ws + 56 * MB);
  float* yout  = (float*)d_out;

  dim3 blk(256);
  dim3 blk512(512);
  // fused prep (one launch)
  prep_kernel<<<7180, blk, 0, stream>>>(Wq, Wk, Wv, Wo, W1, W2, x, bq, bk, bv,
                                        WqkvT, WoT, W1T, W2T, xb, bqkv);
  // G1: fused QKV projection, 256^2 8-phase (16x12 = 192 blocks)
  gemm256_kernel<0><<<dim3(192), blk512, 0, stream>>>(xb, WqkvT, bqkv, QKb, Vt, 3072, 1024, 12);
  // attention
  attn_kernel<<<dim3(32, 16, 2), blk, 0, stream>>>(QKb, Vt, Cb);
  // G2: sa = ctx @ Wo + bo, split-K=2 (bf16 partials) — legacy 128^2
  gemm_kernel<2><<<dim3(8, 32, 2), blk, 0, stream>>>(Cb, WoT, bo, SA0b, SA1b, 1024, 1024, 512);
  // LN1: x1 = LN(sa0 + sa1 + xb) -> bf16
  ln_kernel<0><<<4096, blk, 0, stream>>>(SA0b, SA1b, xb, g1, be1, X1b);
  // G3: h = gelu(x1 @ W1 + b1), 256^2 8-phase (16x16 = 256 blocks)
  gemm256_kernel<1><<<dim3(256), blk512, 0, stream>>>(X1b, W1T, b1, Hb, nullptr, 4096, 1024, 16);
  // G4: y = h @ W2 + b2, split-K=2 (bf16 partials) — legacy 128^2
  gemm_kernel<2><<<dim3(8, 32, 2), blk, 0, stream>>>(Hb, W2T, b2, Y0b, Y1b, 1024, 4096, 2048);
  // LN2: out = LN(y0 + y1 + x1) -> fp32 d_out
  ln_kernel<1><<<4096, blk, 0, stream>>>(Y0b, Y1b, X1b, g2, be2, yout);
}

// Round 2
// 325.922 us; speedup vs baseline: 1.0417x; 1.0417x over previous
//
#include <hip/hip_runtime.h>
#include <cstdint>
#include <math.h>

typedef unsigned short u16;
typedef __attribute__((ext_vector_type(8))) short bf16x8;  // 8 bf16 (4 VGPRs)
typedef __attribute__((ext_vector_type(4))) float f32x4;   // MFMA acc

#define DEVI __device__ __forceinline__

DEVI u16 f2bf(float f) {
  union { float f; uint32_t u; } v; v.f = f;
  return (u16)((v.u + 0x7FFFu + ((v.u >> 16) & 1u)) >> 16);  // RNE
}
DEVI float bf2f(u16 h) {
  union { uint32_t u; float f; } v; v.u = ((uint32_t)h) << 16;
  return v.f;
}

// async global->LDS, 16B per lane. LDS dst = wave-uniform base + lane*16.
DEVI void gload16(const void* g, void* l) {
  __builtin_amdgcn_global_load_lds(
      (const __attribute__((address_space(1))) void*)g,
      (__attribute__((address_space(3))) void*)l, 16, 0, 0);
}

// tanh-form GELU: u*(1 - 1/(1+e^{2*0.79788456*(u+0.044715u^3)}))
DEVI float gelu_fast(float u) {
  float u2 = u * u;
  float t = __builtin_fmaf(0.044715f * u2, u, u);
  float e = __expf(1.5957691216057308f * t);
  float r = __builtin_amdgcn_rcpf(1.0f + e);
  return u - u * r;
}

// ---------------------------------------------------------------------------
// fp32 W[K][N] -> bf16 Wt[N][K] transpose-convert, one 64x64 tile via LDS
// ---------------------------------------------------------------------------
DEVI void tcvt_body(const float* __restrict__ W, u16* __restrict__ Wt,
                    int Kd, int N, int n0, int k0, float* t) {
  const int r = threadIdx.x >> 4, c4 = (threadIdx.x & 15) * 4;
#pragma unroll
  for (int p = 0; p < 4; ++p) {
    int row = p * 16 + r;
    float4 f = *(const float4*)(W + (size_t)(k0 + row) * N + n0 + c4);
    *(float4*)&t[row * 68 + c4] = f;
  }
  __syncthreads();
#pragma unroll
  for (int p = 0; p < 4; ++p) {
    int n = p * 16 + r;
    float v0 = t[(c4 + 0) * 68 + n];
    float v1 = t[(c4 + 1) * 68 + n];
    float v2 = t[(c4 + 2) * 68 + n];
    float v3 = t[(c4 + 3) * 68 + n];
    uint32_t lo = (uint32_t)f2bf(v0) | ((uint32_t)f2bf(v1) << 16);
    uint32_t hi = (uint32_t)f2bf(v2) | ((uint32_t)f2bf(v3) << 16);
    *(uint2*)(Wt + (size_t)(n0 + n) * Kd + k0 + c4) = make_uint2(lo, hi);
  }
}

// ---------------------------------------------------------------------------
// Fused prep: all weight transpose-converts + x convert + bias concat.
// ---------------------------------------------------------------------------
__global__ __launch_bounds__(256)
void prep_kernel(const float* __restrict__ Wq, const float* __restrict__ Wk,
                 const float* __restrict__ Wv, const float* __restrict__ Wo,
                 const float* __restrict__ W1, const float* __restrict__ W2,
                 const float* __restrict__ x, const float* __restrict__ bq,
                 const float* __restrict__ bk, const float* __restrict__ bv,
                 u16* __restrict__ WqkvT, u16* __restrict__ WoT,
                 u16* __restrict__ W1T, u16* __restrict__ W2T,
                 u16* __restrict__ xb, float* __restrict__ bqkv)
{
  __shared__ float t[64 * 68];
  const int b = blockIdx.x;
  if (b < 1024) {
    int wsel = b >> 8, tt = b & 255;
    const float* W = (wsel == 0) ? Wq : (wsel == 1) ? Wk : (wsel == 2) ? Wv : Wo;
    u16* dst = (wsel == 3) ? WoT : WqkvT + (size_t)wsel * 1024 * 1024;
    tcvt_body(W, dst, 1024, 1024, (tt & 15) * 64, (tt >> 4) * 64, t);
  } else if (b < 2048) {
    int tt = b - 1024;
    tcvt_body(W1, W1T, 1024, 4096, (tt & 63) * 64, (tt >> 6) * 64, t);
  } else if (b < 3072) {
    int tt = b - 2048;
    tcvt_body(W2, W2T, 4096, 1024, (tt & 15) * 64, (tt >> 4) * 64, t);
  } else if (b < 7168) {
    int i = ((b - 3072) * 256 + threadIdx.x) * 4;
    float4 f = *(const float4*)(x + i);
    uint32_t lo = (uint32_t)f2bf(f.x) | ((uint32_t)f2bf(f.y) << 16);
    uint32_t hi = (uint32_t)f2bf(f.z) | ((uint32_t)f2bf(f.w) << 16);
    *(uint2*)(xb + i) = make_uint2(lo, hi);
  } else {
    int i = (b - 7168) * 256 + threadIdx.x;  // 0..3071
    const float* s = (i < 1024) ? bq : ((i < 2048) ? bk : bv);
    bqkv[i] = s[i & 1023];
  }
}

// ---------------------------------------------------------------------------
// Legacy GEMM: 128x128 tile, BK=64, 256 thr. Used for G2/G4 (N=1024 shapes).
// ---------------------------------------------------------------------------
template<int MODE>
__global__ __launch_bounds__(256, 4)
void gemm_kernel(const u16* __restrict__ A, const u16* __restrict__ Bt,
                 const float* __restrict__ bias, void* __restrict__ C0,
                 void* __restrict__ C1, int N, int Kfull, int Kpart)
{
  __shared__ u16 As0[128 * 32], As1[128 * 32];
  __shared__ u16 Bs0[128 * 32], Bs1[128 * 32];
  const int tid = threadIdx.x;
  const int nbx = gridDim.x, nby = gridDim.y;
  int lin = blockIdx.y * nbx + blockIdx.x;
  int band = lin / (8 * nbx);
  int rem = lin - band * (8 * nbx);
  int gsz = min(nby - band * 8, 8);
  const int m0 = (band * 8 + rem % gsz) * 128;
  const int n0 = (rem / gsz) * 128;
  const int kbase = (MODE == 2) ? (int)blockIdx.z * Kpart : 0;
  const int w = tid >> 6, lane = tid & 63;
  const int wm = (w >> 1) * 64, wn = (w & 1) * 64;
  const int mr = lane & 15, ko = (lane >> 4) * 8;
  const int rq = (lane >> 4) * 4;
  const int w32 = w * 32;

  f32x4 acc[4][4];
#pragma unroll
  for (int i = 0; i < 4; ++i)
#pragma unroll
    for (int j = 0; j < 4; ++j) {
      f32x4 z = {0.f, 0.f, 0.f, 0.f};
      acc[i][j] = z;
    }

  const int lr = lane >> 2, lk = (lane & 3) * 8;
  const u16* aG = A  + (size_t)(m0 + w32 + lr) * Kfull + kbase + lk;
  const u16* bG = Bt + (size_t)(n0 + w32 + lr) * Kfull + kbase + lk;
  u16* aD00 = &As0[(w32 +  0) * 32];
  u16* aD01 = &As0[(w32 + 16) * 32];
  u16* aD10 = &As1[(w32 +  0) * 32];
  u16* aD11 = &As1[(w32 + 16) * 32];
  u16* bD00 = &Bs0[(w32 +  0) * 32];
  u16* bD01 = &Bs0[(w32 + 16) * 32];
  u16* bD10 = &Bs1[(w32 +  0) * 32];
  u16* bD11 = &Bs1[(w32 + 16) * 32];
  const size_t row16 = (size_t)16 * Kfull;

  for (int k0 = 0; k0 < Kpart; k0 += 64) {
    gload16(aG + k0,              aD00);
    gload16(aG + row16 + k0,      aD01);
    gload16(aG + k0 + 32,         aD10);
    gload16(aG + row16 + k0 + 32, aD11);
    gload16(bG + k0,              bD00);
    gload16(bG + row16 + k0,      bD01);
    gload16(bG + k0 + 32,         bD10);
    gload16(bG + row16 + k0 + 32, bD11);
    __syncthreads();
#pragma unroll
    for (int s = 0; s < 2; ++s) {
      const u16* Ap = s ? As1 : As0;
      const u16* Bp = s ? Bs1 : Bs0;
      bf16x8 af[4], bf[4];
#pragma unroll
      for (int i = 0; i < 4; ++i)
        af[i] = *(const bf16x8*)&Ap[(wm + i * 16 + mr) * 32 + ko];
#pragma unroll
      for (int j = 0; j < 4; ++j)
        bf[j] = *(const bf16x8*)&Bp[(wn + j * 16 + mr) * 32 + ko];
#pragma unroll
      for (int i = 0; i < 4; ++i)
#pragma unroll
        for (int j = 0; j < 4; ++j)
          acc[i][j] = __builtin_amdgcn_mfma_f32_16x16x32_bf16(bf[j], af[i], acc[i][j], 0, 0, 0);
    }
    __syncthreads();
  }

  {
    const bool part1 = (MODE == 2) && (blockIdx.z == 1);
#pragma unroll
    for (int i = 0; i < 4; ++i) {
      size_t mrow = (size_t)(m0 + wm + i * 16 + mr) * N;
#pragma unroll
      for (int j = 0; j < 4; ++j) {
        int nb = n0 + wn + j * 16 + rq;
        float v0 = acc[i][j][0], v1 = acc[i][j][1];
        float v2 = acc[i][j][2], v3 = acc[i][j][3];
        if (!part1) {
          float4 b4 = *(const float4*)&bias[nb];
          v0 += b4.x; v1 += b4.y; v2 += b4.z; v3 += b4.w;
        }
        if (MODE == 1) {
          v0 = gelu_fast(v0); v1 = gelu_fast(v1);
          v2 = gelu_fast(v2); v3 = gelu_fast(v3);
        }
        uint32_t lo = (uint32_t)f2bf(v0) | ((uint32_t)f2bf(v1) << 16);
        uint32_t hi = (uint32_t)f2bf(v2) | ((uint32_t)f2bf(v3) << 16);
        u16* dst = part1 ? (u16*)C1 : (u16*)C0;
        *(uint2*)(dst + mrow + nb) = make_uint2(lo, hi);
      }
    }
  }
}

// ---------------------------------------------------------------------------
// 256x256 8-phase GEMM (T2 swizzle + T3/T4 counted-vmcnt + T5 setprio).
// 512 thr = 8 waves (2m x 4n); per-wave C = 128x64 (acc[8][4] f32x4).
// BK=64; LDS = 2 buf x 2 half x [128 rows x 64 u16] per operand = 128 KiB.
//
// Per K-tile, 4 phases (snake order for register reuse, 24 ds_read/tile/wave):
//   ph1: stage A0',B0' | read aF(A half0, 8) + bF0(B half0, 4) | MFMA q(0,0)
//        | vmcnt(4)  <- drains B1,A1 of THIS tile (issued 3 phases earlier)
//   ph2: stage B1',A1' | read bF1(B half1, 4), reuse aF         | MFMA q(0,1)
//   ph3: read aF(A half1, 8), reuse bF1                         | MFMA q(1,1)
//   ph4: reuse aF + bF0 (0 reads)                               | MFMA q(1,0)
//        | vmcnt(4)  <- drains A0',B0' (issued 3 phases earlier)
// Invariant (induction): entering each tile, outstanding = {B1^t, A1^t} and
// A0^t,B0^t landed. 3-phase slack on every staged half; 2 waits/tile.
// Last tile: no stages; ph1-end vmcnt(0); no other waits.
// MODE 0: fused QKV epilogue (n0<2048 -> QKb packed; else V -> Vt transposed)
// MODE 1: bias + fast GELU -> bf16.
// ---------------------------------------------------------------------------
#define VMW4 asm volatile("s_waitcnt vmcnt(4)" ::: "memory")
#define VMW0 asm volatile("s_waitcnt vmcnt(0)" ::: "memory")
#define BAR  __builtin_amdgcn_s_barrier()
#define PRI1 __builtin_amdgcn_s_setprio(1)
#define PRI0 __builtin_amdgcn_s_setprio(0)

DEVI void stage_half(const u16* __restrict__ G, int row0, int Kfull, int tk,
                     u16* lds_half, int w, int srow, int scol) {
  const u16* s = G + (size_t)(row0 + w * 8 + srow) * Kfull + tk + scol;
  u16* d = lds_half + w * 512;                 // wave-uniform dest
  gload16(s, d);                               // rows [0,64) of the half
  gload16(s + ((size_t)Kfull << 6), d + 4096); // rows [64,128)
}

#define LDA(BASE, HALF)                                                       \
  _Pragma("unroll")                                                           \
  for (int i_ = 0; i_ < 4; ++i_) {                                            \
    const u16* p_ = (BASE) + (HALF) * 8192 + (wm * 64 + i_ * 16 + mr) * 64;   \
    aF[i_][0] = *(const bf16x8*)(p_ + c0);                                    \
    aF[i_][1] = *(const bf16x8*)(p_ + c1);                                    \
  }

#define LDB(BASE, HALF, DST)                                                  \
  _Pragma("unroll")                                                           \
  for (int j_ = 0; j_ < 2; ++j_) {                                            \
    const u16* p_ = (BASE) + (HALF) * 8192 + (wn * 32 + j_ * 16 + mr) * 64;   \
    DST[j_][0] = *(const bf16x8*)(p_ + c0);                                   \
    DST[j_][1] = *(const bf16x8*)(p_ + c1);                                   \
  }

#define MM(MH, NH, BF)                                                        \
  _Pragma("unroll")                                                           \
  for (int i_ = 0; i_ < 4; ++i_)                                              \
    _Pragma("unroll")                                                         \
    for (int j_ = 0; j_ < 2; ++j_) {                                          \
      acc[(MH)*4+i_][(NH)*2+j_] = __builtin_amdgcn_mfma_f32_16x16x32_bf16(    \
          BF[j_][0], aF[i_][0], acc[(MH)*4+i_][(NH)*2+j_], 0, 0, 0);          \
      acc[(MH)*4+i_][(NH)*2+j_] = __builtin_amdgcn_mfma_f32_16x16x32_bf16(    \
          BF[j_][1], aF[i_][1], acc[(MH)*4+i_][(NH)*2+j_], 0, 0, 0);          \
    }

#define TILE(DO_STAGE, W1END, W4END) do {                                     \
    const int cur_ = t & 1, nxt_ = cur_ ^ 1;                                  \
    const int k1_ = (t + 1) << 6;                                             \
    const u16* Ac_ = &As[cur_ * 16384];                                       \
    const u16* Bc_ = &Bs[cur_ * 16384];                                       \
    /* ---- phase 1: quadrant (0,0) ---- */                                   \
    if (DO_STAGE) {                                                           \
      stage_half(A,  m0,       Kfull, k1_, &As[nxt_ * 16384], w, srow, scol); \
      stage_half(Bt, n0,       Kfull, k1_, &Bs[nxt_ * 16384], w, srow, scol); \
    }                                                                         \
    LDA(Ac_, 0);                                                              \
    LDB(Bc_, 0, bF0);                                                         \
    BAR; PRI1; MM(0, 0, bF0); PRI0; W1END; BAR;                               \
    /* ---- phase 2: quadrant (0,1) ---- */                                   \
    if (DO_STAGE) {                                                           \
      stage_half(Bt, n0 + 128, Kfull, k1_, &Bs[nxt_ * 16384 + 8192], w, srow, scol); \
      stage_half(A,  m0 + 128, Kfull, k1_, &As[nxt_ * 16384 + 8192], w, srow, scol); \
    }                                                                         \
    LDB(Bc_, 1, bF1);                                                         \
    BAR; PRI1; MM(0, 1, bF1); PRI0; BAR;                                      \
    /* ---- phase 3: quadrant (1,1) ---- */                                   \
    LDA(Ac_, 1);                                                              \
    BAR; PRI1; MM(1, 1, bF1); PRI0; BAR;                                      \
    /* ---- phase 4: quadrant (1,0), zero ds_reads ---- */                    \
    BAR; PRI1; MM(1, 0, bF0); PRI0; W4END; BAR;                               \
  } while (0)

template<int MODE>
__global__ __launch_bounds__(512, 2)
void gemm256_kernel(const u16* __restrict__ A, const u16* __restrict__ Bt,
                    const float* __restrict__ bias, void* __restrict__ C0,
                    void* __restrict__ C1, int N, int Kfull, int NBN)
{
  __shared__ u16 As[32768];   // 2 buf x 2 half x 128x64
  __shared__ u16 Bs[32768];
  const int tid = threadIdx.x;
  const int w = tid >> 6, lane = tid & 63;
  const int wm = w >> 2, wn = w & 3;           // 2 x 4 waves
  const int mr = lane & 15;
  const int rq = (lane >> 4) * 4;

  // XCD-bijective swizzle (gridDim.x % 8 == 0): same-mt runs share an XCD L2.
  const int lin = blockIdx.x;
  const int q = gridDim.x >> 3;
  const int wg = (lin & 7) * q + (lin >> 3);
  const int mt = wg / NBN, nt = wg - mt * NBN;
  const int m0 = mt * 256, n0 = nt * 256;

  // stage-side mapping (linear LDS dest; inverse-swizzled global source)
  const int srow = lane >> 3;                       // 0..7
  const int scol = ((lane & 7) ^ srow) << 3;        // u16 col within 64
  // read-side swizzled k-columns (u16): byte = (ksub*64 + (lane>>4)*16) ^ ((mr&7)<<4)
  const int bl = (lane >> 4) << 4;
  const int sw = (mr & 7) << 4;
  const int c0 = (bl ^ sw) >> 1;
  const int c1 = ((64 + bl) ^ sw) >> 1;

  f32x4 acc[8][4];
#pragma unroll
  for (int i = 0; i < 8; ++i)
#pragma unroll
    for (int j = 0; j < 4; ++j) {
      f32x4 z = {0.f, 0.f, 0.f, 0.f};
      acc[i][j] = z;
    }

  bf16x8 aF[4][2], bF0[2][2], bF1[2][2];

  const int NT = Kfull >> 6;

  // prologue: tile 0, order A0,B0,B1,A1 -> vmcnt(4) = {A0,B0} landed,
  // {B1,A1} outstanding = steady-state entry invariant.
  stage_half(A,  m0,       Kfull, 0, &As[0],    w, srow, scol);
  stage_half(Bt, n0,       Kfull, 0, &Bs[0],    w, srow, scol);
  stage_half(Bt, n0 + 128, Kfull, 0, &Bs[8192], w, srow, scol);
  stage_half(A,  m0 + 128, Kfull, 0, &As[8192], w, srow, scol);
  VMW4;
  BAR;

  int t = 0;
  for (; t < NT - 1; ++t) {
    TILE(1, VMW4, VMW4);
  }
  TILE(0, VMW0, (void)0);

  // epilogue: m = m0 + (mi>>2)*128 + wm*64 + (mi&3)*16 + mr
  //           n = n0 + (ni>>1)*128 + wn*32 + (ni&1)*16 + rq + r
  if (MODE == 0) {
    if (n0 < 2048) {  // Q,K -> QKb [4096][2048], packed along n
#pragma unroll
      for (int mi = 0; mi < 8; ++mi) {
        int mg = m0 + (mi >> 2) * 128 + wm * 64 + (mi & 3) * 16 + mr;
        size_t mrow = (size_t)mg * 2048;
#pragma unroll
        for (int ni = 0; ni < 4; ++ni) {
          int ng = n0 + (ni >> 1) * 128 + wn * 32 + (ni & 1) * 16 + rq;
          float4 b4 = *(const float4*)&bias[ng];
          f32x4 a = acc[mi][ni];
          uint32_t lo = (uint32_t)f2bf(a[0] + b4.x) | ((uint32_t)f2bf(a[1] + b4.y) << 16);
          uint32_t hi = (uint32_t)f2bf(a[2] + b4.z) | ((uint32_t)f2bf(a[3] + b4.w) << 16);
          *(uint2*)((u16*)C0 + mrow + ng) = make_uint2(lo, hi);
        }
      }
    } else {          // V -> Vt [1024][4096] transposed
#pragma unroll
      for (int mi = 0; mi < 8; ++mi) {
        int mg = m0 + (mi >> 2) * 128 + wm * 64 + (mi & 3) * 16 + mr;
#pragma unroll
        for (int ni = 0; ni < 4; ++ni) {
          int ng = n0 + (ni >> 1) * 128 + wn * 32 + (ni & 1) * 16 + rq;
          float4 b4 = *(const float4*)&bias[ng];
          f32x4 a = acc[mi][ni];
          int d = ng - 2048;
          ((u16*)C1)[(size_t)(d + 0) * 4096 + mg] = f2bf(a[0] + b4.x);
          ((u16*)C1)[(size_t)(d + 1) * 4096 + mg] = f2bf(a[1] + b4.y);
          ((u16*)C1)[(size_t)(d + 2) * 4096 + mg] = f2bf(a[2] + b4.z);
          ((u16*)C1)[(size_t)(d + 3) * 4096 + mg] = f2bf(a[3] + b4.w);
        }
      }
    }
  } else {            // MODE 1: bias + GELU -> bf16
#pragma unroll
    for (int mi = 0; mi < 8; ++mi) {
      int mg = m0 + (mi >> 2) * 128 + wm * 64 + (mi & 3) * 16 + mr;
      size_t mrow = (size_t)mg * N;
#pragma unroll
      for (int ni = 0; ni < 4; ++ni) {
        int ng = n0 + (ni >> 1) * 128 + wn * 32 + (ni & 1) * 16 + rq;
        float4 b4 = *(const float4*)&bias[ng];
        f32x4 a = acc[mi][ni];
        float v0 = gelu_fast(a[0] + b4.x), v1 = gelu_fast(a[1] + b4.y);
        float v2 = gelu_fast(a[2] + b4.z), v3 = gelu_fast(a[3] + b4.w);
        uint32_t lo = (uint32_t)f2bf(v0) | ((uint32_t)f2bf(v1) << 16);
        uint32_t hi = (uint32_t)f2bf(v2) | ((uint32_t)f2bf(v3) << 16);
        *(uint2*)((u16*)C0 + mrow + ng) = make_uint2(lo, hi);
      }
    }
  }
}

// ---------------------------------------------------------------------------
// Banded MFMA flash attention, simplified softmax. QK^T swapped -> S[t][q]:
// lane owns ONE q -> packed b64 P-writes, scalar l. PV swapped -> O[d][q].
// ---------------------------------------------------------------------------
__global__ __launch_bounds__(256)
void attn_kernel(const u16* __restrict__ QKb, const u16* __restrict__ Vt,
                 u16* __restrict__ ctx)
{
  const int KS = 2048, HD = 1024;
  __shared__ u16 Qs[64 * 80];
  __shared__ u16 Ks[64 * 80];
  __shared__ u16 Vts[64 * 72];   // [d][t]
  __shared__ u16 Ps[64 * 72];    // [q][t]

  const int qt = blockIdx.x, hh = blockIdx.y, bb = blockIdx.z;
  const int s0 = qt * 64;
  const int tid = threadIdx.x, w = tid >> 6, lane = tid & 63;
  const int mr = lane & 15, ko = (lane >> 4) * 8, rq = (lane >> 4) * 4;
  const int sr = tid >> 3, sc = (tid & 7) * 8;
  const int vrow = tid >> 2, vtc = (tid & 3) * 16;
  const float qsc = 0.022097086912079608f;  // 1/sqrt(2048)
  const int qg = s0 + w * 16 + mr;          // this lane's query row

#pragma unroll
  for (int p = 0; p < 2; ++p) {
    int row = p * 32 + sr;
    uint4 u = *(const uint4*)(QKb + (size_t)(bb * KS + s0 + row) * 2048 + hh * 64 + sc);
    *(uint4*)&Qs[row * 80 + sc] = u;
  }

  f32x4 accO[4];
#pragma unroll
  for (int j = 0; j < 4; ++j) { f32x4 z = {0.f,0.f,0.f,0.f}; accO[j] = z; }
  float lsum = 0.f;

  for (int c = 0; c < 9; ++c) {
    int tb = s0 - 256 + c * 64;
    if (tb < 0 || tb >= KS) continue;
    __syncthreads();
#pragma unroll
    for (int p = 0; p < 2; ++p) {
      int row = p * 32 + sr;
      uint4 uk = *(const uint4*)(QKb + (size_t)(bb * KS + tb + row) * 2048 + 1024 + hh * 64 + sc);
      *(uint4*)&Ks[row * 80 + sc] = uk;
    }
    {
      const u16* vsrc = Vt + (size_t)(hh * 64 + vrow) * 4096 + bb * KS + tb + vtc;
      *(uint4*)&Vts[vrow * 72 + vtc]     = *(const uint4*)vsrc;
      *(uint4*)&Vts[vrow * 72 + vtc + 8] = *(const uint4*)(vsrc + 8);
    }
    __syncthreads();

    f32x4 sacc[4];
#pragma unroll
    for (int j = 0; j < 4; ++j) { f32x4 z = {0.f,0.f,0.f,0.f}; sacc[j] = z; }
#pragma unroll
    for (int s = 0; s < 2; ++s) {
      bf16x8 aq = *(const bf16x8*)&Qs[(w * 16 + mr) * 80 + s * 32 + ko];
#pragma unroll
      for (int j = 0; j < 4; ++j) {
        bf16x8 bk = *(const bf16x8*)&Ks[(j * 16 + mr) * 80 + s * 32 + ko];
        sacc[j] = __builtin_amdgcn_mfma_f32_16x16x32_bf16(bk, aq, sacc[j], 0, 0, 0);
      }
    }

#pragma unroll
    for (int j = 0; j < 4; ++j) {
      int tgb = tb + j * 16 + rq;
      float p0, p1, p2, p3;
      {
        int d0 = qg - tgb;
        float s_ = sacc[j][0] * qsc;
        p0 = (d0 > 256 || d0 < -256) ? 0.f : __expf(s_);
        int d1 = d0 - 1; s_ = sacc[j][1] * qsc;
        p1 = (d1 > 256 || d1 < -256) ? 0.f : __expf(s_);
        int d2 = d0 - 2; s_ = sacc[j][2] * qsc;
        p2 = (d2 > 256 || d2 < -256) ? 0.f : __expf(s_);
        int d3 = d0 - 3; s_ = sacc[j][3] * qsc;
        p3 = (d3 > 256 || d3 < -256) ? 0.f : __expf(s_);
      }
      lsum += p0 + p1 + p2 + p3;
      uint32_t lo = (uint32_t)f2bf(p0) | ((uint32_t)f2bf(p1) << 16);
      uint32_t hi = (uint32_t)f2bf(p2) | ((uint32_t)f2bf(p3) << 16);
      *(uint2*)&Ps[(w * 16 + mr) * 72 + j * 16 + rq] = make_uint2(lo, hi);
    }
#pragma unroll
    for (int s = 0; s < 2; ++s) {
      bf16x8 ap = *(const bf16x8*)&Ps[(w * 16 + mr) * 72 + s * 32 + ko];
#pragma unroll
      for (int j = 0; j < 4; ++j) {
        bf16x8 bv = *(const bf16x8*)&Vts[(j * 16 + mr) * 72 + s * 32 + ko];
        accO[j] = __builtin_amdgcn_mfma_f32_16x16x32_bf16(bv, ap, accO[j], 0, 0, 0);
      }
    }
  }

  float l = lsum;
  l += __shfl_xor(l, 16, 64);
  l += __shfl_xor(l, 32, 64);
  float inv = 1.f / l;
  size_t base = (size_t)(bb * KS + qg) * HD + hh * 64;
#pragma unroll
  for (int j = 0; j < 4; ++j) {
    uint32_t lo = (uint32_t)f2bf(accO[j][0] * inv) | ((uint32_t)f2bf(accO[j][1] * inv) << 16);
    uint32_t hi = (uint32_t)f2bf(accO[j][2] * inv) | ((uint32_t)f2bf(accO[j][3] * inv) << 16);
    *(uint2*)(ctx + base + j * 16 + rq) = make_uint2(lo, hi);
  }
}

// ---------------------------------------------------------------------------
// LayerNorm(p0 + p1 + res) over D=1024; all inputs bf16.
// ---------------------------------------------------------------------------
DEVI void bfadd4(const u16* p, size_t base, float& v0, float& v1, float& v2, float& v3) {
  uint2 u = *(const uint2*)(p + base);
  v0 += bf2f((u16)(u.x & 0xFFFFu));
  v1 += bf2f((u16)(u.x >> 16));
  v2 += bf2f((u16)(u.y & 0xFFFFu));
  v3 += bf2f((u16)(u.y >> 16));
}

template<int OUT32>
__global__ __launch_bounds__(256)
void ln_kernel(const u16* __restrict__ p0, const u16* __restrict__ p1,
               const u16* __restrict__ res, const float* __restrict__ g,
               const float* __restrict__ be, void* __restrict__ out)
{
  __shared__ float red[8];
  const int row = blockIdx.x, tid = threadIdx.x;
  const int w = tid >> 6, lane = tid & 63;
  size_t base = (size_t)row * 1024 + tid * 4;
  float v0 = 0.f, v1 = 0.f, v2 = 0.f, v3 = 0.f;
  bfadd4(p0, base, v0, v1, v2, v3);
  bfadd4(p1, base, v0, v1, v2, v3);
  bfadd4(res, base, v0, v1, v2, v3);
  float s1 = v0 + v1 + v2 + v3;
  float s2 = v0 * v0 + v1 * v1 + v2 * v2 + v3 * v3;
#pragma unroll
  for (int o = 32; o > 0; o >>= 1) {
    s1 += __shfl_xor(s1, o, 64);
    s2 += __shfl_xor(s2, o, 64);
  }
  if (lane == 0) { red[w] = s1; red[4 + w] = s2; }
  __syncthreads();
  s1 = red[0] + red[1] + red[2] + red[3];
  s2 = red[4] + red[5] + red[6] + red[7];
  float mu = s1 * (1.f / 1024.f);
  float var = s2 * (1.f / 1024.f) - mu * mu;
  float rs = rsqrtf(var + 1e-5f);
  float4 gv = *(const float4*)(g + tid * 4);
  float4 bv = *(const float4*)(be + tid * 4);
  float o0 = (v0 - mu) * rs * gv.x + bv.x;
  float o1 = (v1 - mu) * rs * gv.y + bv.y;
  float o2 = (v2 - mu) * rs * gv.z + bv.z;
  float o3 = (v3 - mu) * rs * gv.w + bv.w;
  if (OUT32) {
    float4 ov; ov.x = o0; ov.y = o1; ov.z = o2; ov.w = o3;
    *(float4*)((float*)out + base) = ov;
  } else {
    uint32_t lo = (uint32_t)f2bf(o0) | ((uint32_t)f2bf(o1) << 16);
    uint32_t hi = (uint32_t)f2bf(o2) | ((uint32_t)f2bf(o3) << 16);
    *(uint2*)((u16*)out + base) = make_uint2(lo, hi);
  }
}

// ---------------------------------------------------------------------------
// ws layout (64 MiB), MiB offsets, lifetime-verified (unchanged):
//  [0,8)   W1T -> Y0b;  [8,16) xb -> Y1b;  [16,24) WqkvT/WoT -> X1b
//  [24,40) QKb -> SA0b/SA1b -> Hb[lo];  [40,48) Vt -> Hb[mid]
//  [48,56) bqkv -> Cb -> Hb[hi];  [56,64) W2T
// ---------------------------------------------------------------------------
extern "C" void kernel_launch(void* const* d_in, const int* in_sizes, int n_in,
                              void* d_out, int out_size, void* d_ws, size_t ws_size,
                              hipStream_t stream)
{
  (void)in_sizes; (void)n_in; (void)out_size; (void)ws_size;
  const float* x   = (const float*)d_in[0];
  const float* Wq  = (const float*)d_in[1];
  const float* bq  = (const float*)d_in[2];
  const float* Wk  = (const float*)d_in[3];
  const float* bk  = (const float*)d_in[4];
  const float* Wv  = (const float*)d_in[5];
  const float* bv  = (const float*)d_in[6];
  const float* Wo  = (const float*)d_in[7];
  const float* bo  = (const float*)d_in[8];
  const float* W1  = (const float*)d_in[9];
  const float* b1  = (const float*)d_in[10];
  const float* W2  = (const float*)d_in[11];
  const float* b2  = (const float*)d_in[12];
  const float* g1  = (const float*)d_in[13];
  const float* be1 = (const float*)d_in[14];
  const float* g2  = (const float*)d_in[15];
  const float* be2 = (const float*)d_in[16];

  char* ws = (char*)d_ws;
  const size_t MB = 1048576;
  u16*   W1T   = (u16*)(ws + 0 * MB);
  u16*   Y0b   = (u16*)(ws + 0 * MB);
  u16*   xb    = (u16*)(ws + 8 * MB);
  u16*   Y1b   = (u16*)(ws + 8 * MB);
  u16*   WqkvT = (u16*)(ws + 16 * MB);
  u16*   X1b   = (u16*)(ws + 16 * MB);
  u16*   WoT   = (u16*)(ws + 22 * MB);
  u16*   QKb   = (u16*)(ws + 24 * MB);
  u16*   SA0b  = (u16*)(ws + 24 * MB);
  u16*   SA1b  = (u16*)(ws + 32 * MB);
  u16*   Hb    = (u16*)(ws + 24 * MB);
  u16*   Vt    = (u16*)(ws + 40 * MB);
  float* bqkv  = (float*)(ws + 48 * MB);
  u16*   Cb    = (u16*)(ws + 48 * MB);
  u16*   W2T   = (u16*)(ws + 56 * MB);
  float* yout  = (float*)d_out;

  dim3 blk(256);
  dim3 blk512(512);
  // fused prep (one launch)
  prep_kernel<<<7180, blk, 0, stream>>>(Wq, Wk, Wv, Wo, W1, W2, x, bq, bk, bv,
                                        WqkvT, WoT, W1T, W2T, xb, bqkv);
  // G1: fused QKV projection, 256^2 4-phase reuse (16x12 = 192 blocks)
  gemm256_kernel<0><<<dim3(192), blk512, 0, stream>>>(xb, WqkvT, bqkv, QKb, Vt, 3072, 1024, 12);
  // attention
  attn_kernel<<<dim3(32, 16, 2), blk, 0, stream>>>(QKb, Vt, Cb);
  // G2: sa = ctx @ Wo + bo, split-K=2 (bf16 partials) — legacy 128^2
  gemm_kernel<2><<<dim3(8, 32, 2), blk, 0, stream>>>(Cb, WoT, bo, SA0b, SA1b, 1024, 1024, 512);
  // LN1: x1 = LN(sa0 + sa1 + xb) -> bf16
  ln_kernel<0><<<4096, blk, 0, stream>>>(SA0b, SA1b, xb, g1, be1, X1b);
  // G3: h = gelu(x1 @ W1 + b1), 256^2 4-phase reuse (16x16 = 256 blocks)
  gemm256_kernel<1><<<dim3(256), blk512, 0, stream>>>(X1b, W1T, b1, Hb, nullptr, 4096, 1024, 16);
  // G4: y = h @ W2 + b2, split-K=2 (bf16 partials) — legacy 128^2
  gemm_kernel<2><<<dim3(8, 32, 2), blk, 0, stream>>>(Hb, W2T, b2, Y0b, Y1b, 1024, 4096, 2048);
  // LN2: out = LN(y0 + y1 + x1) -> fp32 d_out
  ln_kernel<1><<<4096, blk, 0, stream>>>(Y0b, Y1b, X1b, g2, be2, yout);
}

// Round 4
// 325.683 us; speedup vs baseline: 1.0425x; 1.0007x over previous
//
#include <hip/hip_runtime.h>
#include <cstdint>
#include <math.h>

typedef unsigned short u16;
typedef __attribute__((ext_vector_type(8))) short bf16x8;  // 8 bf16 (4 VGPRs)
typedef __attribute__((ext_vector_type(4))) float f32x4;   // MFMA acc

#define DEVI __device__ __forceinline__

DEVI u16 f2bf(float f) {
  union { float f; uint32_t u; } v; v.f = f;
  return (u16)((v.u + 0x7FFFu + ((v.u >> 16) & 1u)) >> 16);  // RNE
}
DEVI float bf2f(u16 h) {
  union { uint32_t u; float f; } v; v.u = ((uint32_t)h) << 16;
  return v.f;
}

// async global->LDS, 16B per lane. LDS dst = wave-uniform base + lane*16.
DEVI void gload16(const void* g, void* l) {
  __builtin_amdgcn_global_load_lds(
      (const __attribute__((address_space(1))) void*)g,
      (__attribute__((address_space(3))) void*)l, 16, 0, 0);
}

// tanh-form GELU: u*(1 - 1/(1+e^{2*0.79788456*(u+0.044715u^3)}))
DEVI float gelu_fast(float u) {
  float u2 = u * u;
  float t = __builtin_fmaf(0.044715f * u2, u, u);
  float e = __expf(1.5957691216057308f * t);
  float r = __builtin_amdgcn_rcpf(1.0f + e);
  return u - u * r;
}

// ---------------------------------------------------------------------------
// fp32 W[K][N] -> bf16 Wt[N][K] transpose-convert, one 64x64 tile via LDS
// ---------------------------------------------------------------------------
DEVI void tcvt_body(const float* __restrict__ W, u16* __restrict__ Wt,
                    int Kd, int N, int n0, int k0, float* t) {
  const int r = threadIdx.x >> 4, c4 = (threadIdx.x & 15) * 4;
#pragma unroll
  for (int p = 0; p < 4; ++p) {
    int row = p * 16 + r;
    float4 f = *(const float4*)(W + (size_t)(k0 + row) * N + n0 + c4);
    *(float4*)&t[row * 68 + c4] = f;
  }
  __syncthreads();
#pragma unroll
  for (int p = 0; p < 4; ++p) {
    int n = p * 16 + r;
    float v0 = t[(c4 + 0) * 68 + n];
    float v1 = t[(c4 + 1) * 68 + n];
    float v2 = t[(c4 + 2) * 68 + n];
    float v3 = t[(c4 + 3) * 68 + n];
    uint32_t lo = (uint32_t)f2bf(v0) | ((uint32_t)f2bf(v1) << 16);
    uint32_t hi = (uint32_t)f2bf(v2) | ((uint32_t)f2bf(v3) << 16);
    *(uint2*)(Wt + (size_t)(n0 + n) * Kd + k0 + c4) = make_uint2(lo, hi);
  }
}

// ---------------------------------------------------------------------------
// Fused prep: all weight transpose-converts + x convert + bias concat.
// ---------------------------------------------------------------------------
__global__ __launch_bounds__(256)
void prep_kernel(const float* __restrict__ Wq, const float* __restrict__ Wk,
                 const float* __restrict__ Wv, const float* __restrict__ Wo,
                 const float* __restrict__ W1, const float* __restrict__ W2,
                 const float* __restrict__ x, const float* __restrict__ bq,
                 const float* __restrict__ bk, const float* __restrict__ bv,
                 u16* __restrict__ WqkvT, u16* __restrict__ WoT,
                 u16* __restrict__ W1T, u16* __restrict__ W2T,
                 u16* __restrict__ xb, float* __restrict__ bqkv)
{
  __shared__ float t[64 * 68];
  const int b = blockIdx.x;
  if (b < 1024) {
    int wsel = b >> 8, tt = b & 255;
    const float* W = (wsel == 0) ? Wq : (wsel == 1) ? Wk : (wsel == 2) ? Wv : Wo;
    u16* dst = (wsel == 3) ? WoT : WqkvT + (size_t)wsel * 1024 * 1024;
    tcvt_body(W, dst, 1024, 1024, (tt & 15) * 64, (tt >> 4) * 64, t);
  } else if (b < 2048) {
    int tt = b - 1024;
    tcvt_body(W1, W1T, 1024, 4096, (tt & 63) * 64, (tt >> 6) * 64, t);
  } else if (b < 3072) {
    int tt = b - 2048;
    tcvt_body(W2, W2T, 4096, 1024, (tt & 15) * 64, (tt >> 4) * 64, t);
  } else if (b < 7168) {
    int i = ((b - 3072) * 256 + threadIdx.x) * 4;
    float4 f = *(const float4*)(x + i);
    uint32_t lo = (uint32_t)f2bf(f.x) | ((uint32_t)f2bf(f.y) << 16);
    uint32_t hi = (uint32_t)f2bf(f.z) | ((uint32_t)f2bf(f.w) << 16);
    *(uint2*)(xb + i) = make_uint2(lo, hi);
  } else {
    int i = (b - 7168) * 256 + threadIdx.x;  // 0..3071
    const float* s = (i < 1024) ? bq : ((i < 2048) ? bk : bv);
    bqkv[i] = s[i & 1023];
  }
}

// ---------------------------------------------------------------------------
// Legacy GEMM: 128x128 tile, BK=64, 256 thr. Used for G2/G4 (N=1024 shapes).
// ---------------------------------------------------------------------------
template<int MODE>
__global__ __launch_bounds__(256, 4)
void gemm_kernel(const u16* __restrict__ A, const u16* __restrict__ Bt,
                 const float* __restrict__ bias, void* __restrict__ C0,
                 void* __restrict__ C1, int N, int Kfull, int Kpart)
{
  __shared__ u16 As0[128 * 32], As1[128 * 32];
  __shared__ u16 Bs0[128 * 32], Bs1[128 * 32];
  const int tid = threadIdx.x;
  const int nbx = gridDim.x, nby = gridDim.y;
  int lin = blockIdx.y * nbx + blockIdx.x;
  int band = lin / (8 * nbx);
  int rem = lin - band * (8 * nbx);
  int gsz = min(nby - band * 8, 8);
  const int m0 = (band * 8 + rem % gsz) * 128;
  const int n0 = (rem / gsz) * 128;
  const int kbase = (MODE == 2) ? (int)blockIdx.z * Kpart : 0;
  const int w = tid >> 6, lane = tid & 63;
  const int wm = (w >> 1) * 64, wn = (w & 1) * 64;
  const int mr = lane & 15, ko = (lane >> 4) * 8;
  const int rq = (lane >> 4) * 4;
  const int w32 = w * 32;

  f32x4 acc[4][4];
#pragma unroll
  for (int i = 0; i < 4; ++i)
#pragma unroll
    for (int j = 0; j < 4; ++j) {
      f32x4 z = {0.f, 0.f, 0.f, 0.f};
      acc[i][j] = z;
    }

  const int lr = lane >> 2, lk = (lane & 3) * 8;
  const u16* aG = A  + (size_t)(m0 + w32 + lr) * Kfull + kbase + lk;
  const u16* bG = Bt + (size_t)(n0 + w32 + lr) * Kfull + kbase + lk;
  u16* aD00 = &As0[(w32 +  0) * 32];
  u16* aD01 = &As0[(w32 + 16) * 32];
  u16* aD10 = &As1[(w32 +  0) * 32];
  u16* aD11 = &As1[(w32 + 16) * 32];
  u16* bD00 = &Bs0[(w32 +  0) * 32];
  u16* bD01 = &Bs0[(w32 + 16) * 32];
  u16* bD10 = &Bs1[(w32 +  0) * 32];
  u16* bD11 = &Bs1[(w32 + 16) * 32];
  const size_t row16 = (size_t)16 * Kfull;

  for (int k0 = 0; k0 < Kpart; k0 += 64) {
    gload16(aG + k0,              aD00);
    gload16(aG + row16 + k0,      aD01);
    gload16(aG + k0 + 32,         aD10);
    gload16(aG + row16 + k0 + 32, aD11);
    gload16(bG + k0,              bD00);
    gload16(bG + row16 + k0,      bD01);
    gload16(bG + k0 + 32,         bD10);
    gload16(bG + row16 + k0 + 32, bD11);
    __syncthreads();
#pragma unroll
    for (int s = 0; s < 2; ++s) {
      const u16* Ap = s ? As1 : As0;
      const u16* Bp = s ? Bs1 : Bs0;
      bf16x8 af[4], bf[4];
#pragma unroll
      for (int i = 0; i < 4; ++i)
        af[i] = *(const bf16x8*)&Ap[(wm + i * 16 + mr) * 32 + ko];
#pragma unroll
      for (int j = 0; j < 4; ++j)
        bf[j] = *(const bf16x8*)&Bp[(wn + j * 16 + mr) * 32 + ko];
#pragma unroll
      for (int i = 0; i < 4; ++i)
#pragma unroll
        for (int j = 0; j < 4; ++j)
          acc[i][j] = __builtin_amdgcn_mfma_f32_16x16x32_bf16(bf[j], af[i], acc[i][j], 0, 0, 0);
    }
    __syncthreads();
  }

  {
    const bool part1 = (MODE == 2) && (blockIdx.z == 1);
#pragma unroll
    for (int i = 0; i < 4; ++i) {
      size_t mrow = (size_t)(m0 + wm + i * 16 + mr) * N;
#pragma unroll
      for (int j = 0; j < 4; ++j) {
        int nb = n0 + wn + j * 16 + rq;
        float v0 = acc[i][j][0], v1 = acc[i][j][1];
        float v2 = acc[i][j][2], v3 = acc[i][j][3];
        if (!part1) {
          float4 b4 = *(const float4*)&bias[nb];
          v0 += b4.x; v1 += b4.y; v2 += b4.z; v3 += b4.w;
        }
        if (MODE == 1) {
          v0 = gelu_fast(v0); v1 = gelu_fast(v1);
          v2 = gelu_fast(v2); v3 = gelu_fast(v3);
        }
        uint32_t lo = (uint32_t)f2bf(v0) | ((uint32_t)f2bf(v1) << 16);
        uint32_t hi = (uint32_t)f2bf(v2) | ((uint32_t)f2bf(v3) << 16);
        u16* dst = part1 ? (u16*)C1 : (u16*)C0;
        *(uint2*)(dst + mrow + nb) = make_uint2(lo, hi);
      }
    }
  }
}

// ---------------------------------------------------------------------------
// 256x256 GEMM, free-running tile schedule (2 barriers/K-tile).
// 512 thr = 8 waves (2m x 4n); per-wave C = 128x64 (acc[8][4] f32x4).
// BK=64; LDS = 2 buf x 2 half x [128 rows x 64 u16] per operand = 128 KiB.
//
// Hazard analysis: within a tile, ALL ds_reads hit buf cur (staged+published
// before tile entry) and ALL gload_lds stages write buf nxt (read by nobody
// this tile). So intra-phase barriers serve no hazard: keep only
//   (a) mid-tile:  vmcnt(4) drains B1^t,A1^t  + barrier -> publishes cur half1
//       before its first ds_read (RAW, cross-wave);
//   (b) tile-end:  vmcnt(4) drains A0',B0'    + barrier -> publishes nxt half0
//       AND fences WAR (tile t+1 stages rewrite cur; all tile-t ds_reads are
//       register-consumed by MFMAs before this barrier).
// vmcnt ledger (stage_half = 2 loads; stages A0',B0' then B1',A1'):
//   before (a): {B1,A1, A0',B0'} = 8 -> vmcnt(4) drains oldest 4 = B1,A1.
//   before (b): {A0',B0', B1',A1'} = 8 -> vmcnt(4) drains A0',B0'.
// 3-phase slack on every staged half. Waves free-run between barriers ->
// LDS reads of one wave overlap MFMA of another (TLP) + compiler interleaves
// reads into the MFMA stream (ILP). Last tile: no stages; vmcnt(0) at (a).
// MODE 0: fused QKV epilogue (n0<2048 -> QKb packed; else V -> Vt transposed)
// MODE 1: bias + fast GELU -> bf16.
// ---------------------------------------------------------------------------
#define VMW4 asm volatile("s_waitcnt vmcnt(4)" ::: "memory")
#define VMW0 asm volatile("s_waitcnt vmcnt(0)" ::: "memory")
#define BAR  __builtin_amdgcn_s_barrier()
#define PRI1 __builtin_amdgcn_s_setprio(1)
#define PRI0 __builtin_amdgcn_s_setprio(0)

DEVI void stage_half(const u16* __restrict__ G, int row0, int Kfull, int tk,
                     u16* lds_half, int w, int srow, int scol) {
  const u16* s = G + (size_t)(row0 + w * 8 + srow) * Kfull + tk + scol;
  u16* d = lds_half + w * 512;                 // wave-uniform dest
  gload16(s, d);                               // rows [0,64) of the half
  gload16(s + ((size_t)Kfull << 6), d + 4096); // rows [64,128)
}

#define LDA(BASE, HALF)                                                       \
  _Pragma("unroll")                                                           \
  for (int i_ = 0; i_ < 4; ++i_) {                                            \
    const u16* p_ = (BASE) + (HALF) * 8192 + (wm * 64 + i_ * 16 + mr) * 64;   \
    aF[i_][0] = *(const bf16x8*)(p_ + c0);                                    \
    aF[i_][1] = *(const bf16x8*)(p_ + c1);                                    \
  }

#define LDB(BASE, HALF, DST)                                                  \
  _Pragma("unroll")                                                           \
  for (int j_ = 0; j_ < 2; ++j_) {                                            \
    const u16* p_ = (BASE) + (HALF) * 8192 + (wn * 32 + j_ * 16 + mr) * 64;   \
    DST[j_][0] = *(const bf16x8*)(p_ + c0);                                   \
    DST[j_][1] = *(const bf16x8*)(p_ + c1);                                   \
  }

#define MM(MH, NH, BF)                                                        \
  PRI1;                                                                       \
  _Pragma("unroll")                                                           \
  for (int i_ = 0; i_ < 4; ++i_)                                              \
    _Pragma("unroll")                                                         \
    for (int j_ = 0; j_ < 2; ++j_) {                                          \
      acc[(MH)*4+i_][(NH)*2+j_] = __builtin_amdgcn_mfma_f32_16x16x32_bf16(    \
          BF[j_][0], aF[i_][0], acc[(MH)*4+i_][(NH)*2+j_], 0, 0, 0);          \
      acc[(MH)*4+i_][(NH)*2+j_] = __builtin_amdgcn_mfma_f32_16x16x32_bf16(    \
          BF[j_][1], aF[i_][1], acc[(MH)*4+i_][(NH)*2+j_], 0, 0, 0);          \
    }                                                                         \
  PRI0;

#define TILE(DO_STAGE, WA, WB) do {                                           \
    const int cur_ = t & 1, nxt_ = cur_ ^ 1;                                  \
    const int k1_ = (t + 1) << 6;                                             \
    const u16* Ac_ = &As[cur_ * 16384];                                       \
    const u16* Bc_ = &Bs[cur_ * 16384];                                       \
    if (DO_STAGE) {                                                           \
      stage_half(A,  m0,       Kfull, k1_, &As[nxt_ * 16384], w, srow, scol); \
      stage_half(Bt, n0,       Kfull, k1_, &Bs[nxt_ * 16384], w, srow, scol); \
    }                                                                         \
    LDA(Ac_, 0);                                                              \
    LDB(Bc_, 0, bF0);                                                         \
    MM(0, 0, bF0);                                                            \
    WA;                                                                       \
    BAR;   /* (a) publish cur half1 */                                        \
    if (DO_STAGE) {                                                           \
      stage_half(Bt, n0 + 128, Kfull, k1_, &Bs[nxt_ * 16384 + 8192], w, srow, scol); \
      stage_half(A,  m0 + 128, Kfull, k1_, &As[nxt_ * 16384 + 8192], w, srow, scol); \
    }                                                                         \
    LDB(Bc_, 1, bF1);                                                         \
    MM(0, 1, bF1);                                                            \
    LDA(Ac_, 1);                                                              \
    MM(1, 1, bF1);                                                            \
    MM(1, 0, bF0);                                                            \
    WB;                                                                       \
    BAR;   /* (b) publish nxt half0 + WAR fence on cur */                     \
  } while (0)

template<int MODE>
__global__ __launch_bounds__(512, 2)
void gemm256_kernel(const u16* __restrict__ A, const u16* __restrict__ Bt,
                    const float* __restrict__ bias, void* __restrict__ C0,
                    void* __restrict__ C1, int N, int Kfull, int NBN)
{
  __shared__ u16 As[32768];   // 2 buf x 2 half x 128x64
  __shared__ u16 Bs[32768];
  const int tid = threadIdx.x;
  const int w = tid >> 6, lane = tid & 63;
  const int wm = w >> 2, wn = w & 3;           // 2 x 4 waves
  const int mr = lane & 15;
  const int rq = (lane >> 4) * 4;

  // XCD-bijective swizzle (gridDim.x % 8 == 0): same-mt runs share an XCD L2.
  const int lin = blockIdx.x;
  const int q = gridDim.x >> 3;
  const int wg = (lin & 7) * q + (lin >> 3);
  const int mt = wg / NBN, nt = wg - mt * NBN;
  const int m0 = mt * 256, n0 = nt * 256;

  // stage-side mapping (linear LDS dest; inverse-swizzled global source)
  const int srow = lane >> 3;                       // 0..7
  const int scol = ((lane & 7) ^ srow) << 3;        // u16 col within 64
  // read-side swizzled k-columns (u16): byte = (ksub*64 + (lane>>4)*16) ^ ((mr&7)<<4)
  const int bl = (lane >> 4) << 4;
  const int sw = (mr & 7) << 4;
  const int c0 = (bl ^ sw) >> 1;
  const int c1 = ((64 + bl) ^ sw) >> 1;

  f32x4 acc[8][4];
#pragma unroll
  for (int i = 0; i < 8; ++i)
#pragma unroll
    for (int j = 0; j < 4; ++j) {
      f32x4 z = {0.f, 0.f, 0.f, 0.f};
      acc[i][j] = z;
    }

  bf16x8 aF[4][2], bF0[2][2], bF1[2][2];

  const int NT = Kfull >> 6;

  // prologue: tile 0, order A0,B0,B1,A1 -> vmcnt(4) = {A0,B0} landed,
  // {B1,A1} outstanding = steady-state entry invariant.
  stage_half(A,  m0,       Kfull, 0, &As[0],    w, srow, scol);
  stage_half(Bt, n0,       Kfull, 0, &Bs[0],    w, srow, scol);
  stage_half(Bt, n0 + 128, Kfull, 0, &Bs[8192], w, srow, scol);
  stage_half(A,  m0 + 128, Kfull, 0, &As[8192], w, srow, scol);
  VMW4;
  BAR;

  int t = 0;
  for (; t < NT - 1; ++t) {
    TILE(1, VMW4, VMW4);
  }
  TILE(0, VMW0, (void)0);

  // epilogue: m = m0 + (mi>>2)*128 + wm*64 + (mi&3)*16 + mr
  //           n = n0 + (ni>>1)*128 + wn*32 + (ni&1)*16 + rq + r
  if (MODE == 0) {
    if (n0 < 2048) {  // Q,K -> QKb [4096][2048], packed along n
#pragma unroll
      for (int mi = 0; mi < 8; ++mi) {
        int mg = m0 + (mi >> 2) * 128 + wm * 64 + (mi & 3) * 16 + mr;
        size_t mrow = (size_t)mg * 2048;
#pragma unroll
        for (int ni = 0; ni < 4; ++ni) {
          int ng = n0 + (ni >> 1) * 128 + wn * 32 + (ni & 1) * 16 + rq;
          float4 b4 = *(const float4*)&bias[ng];
          f32x4 a = acc[mi][ni];
          uint32_t lo = (uint32_t)f2bf(a[0] + b4.x) | ((uint32_t)f2bf(a[1] + b4.y) << 16);
          uint32_t hi = (uint32_t)f2bf(a[2] + b4.z) | ((uint32_t)f2bf(a[3] + b4.w) << 16);
          *(uint2*)((u16*)C0 + mrow + ng) = make_uint2(lo, hi);
        }
      }
    } else {          // V -> Vt [1024][4096] transposed
#pragma unroll
      for (int mi = 0; mi < 8; ++mi) {
        int mg = m0 + (mi >> 2) * 128 + wm * 64 + (mi & 3) * 16 + mr;
#pragma unroll
        for (int ni = 0; ni < 4; ++ni) {
          int ng = n0 + (ni >> 1) * 128 + wn * 32 + (ni & 1) * 16 + rq;
          float4 b4 = *(const float4*)&bias[ng];
          f32x4 a = acc[mi][ni];
          int d = ng - 2048;
          ((u16*)C1)[(size_t)(d + 0) * 4096 + mg] = f2bf(a[0] + b4.x);
          ((u16*)C1)[(size_t)(d + 1) * 4096 + mg] = f2bf(a[1] + b4.y);
          ((u16*)C1)[(size_t)(d + 2) * 4096 + mg] = f2bf(a[2] + b4.z);
          ((u16*)C1)[(size_t)(d + 3) * 4096 + mg] = f2bf(a[3] + b4.w);
        }
      }
    }
  } else {            // MODE 1: bias + GELU -> bf16
#pragma unroll
    for (int mi = 0; mi < 8; ++mi) {
      int mg = m0 + (mi >> 2) * 128 + wm * 64 + (mi & 3) * 16 + mr;
      size_t mrow = (size_t)mg * N;
#pragma unroll
      for (int ni = 0; ni < 4; ++ni) {
        int ng = n0 + (ni >> 1) * 128 + wn * 32 + (ni & 1) * 16 + rq;
        float4 b4 = *(const float4*)&bias[ng];
        f32x4 a = acc[mi][ni];
        float v0 = gelu_fast(a[0] + b4.x), v1 = gelu_fast(a[1] + b4.y);
        float v2 = gelu_fast(a[2] + b4.z), v3 = gelu_fast(a[3] + b4.w);
        uint32_t lo = (uint32_t)f2bf(v0) | ((uint32_t)f2bf(v1) << 16);
        uint32_t hi = (uint32_t)f2bf(v2) | ((uint32_t)f2bf(v3) << 16);
        *(uint2*)((u16*)C0 + mrow + ng) = make_uint2(lo, hi);
      }
    }
  }
}

// ---------------------------------------------------------------------------
// Banded MFMA flash attention, simplified softmax. QK^T swapped -> S[t][q]:
// lane owns ONE q -> packed b64 P-writes, scalar l. PV swapped -> O[d][q].
// ---------------------------------------------------------------------------
__global__ __launch_bounds__(256)
void attn_kernel(const u16* __restrict__ QKb, const u16* __restrict__ Vt,
                 u16* __restrict__ ctx)
{
  const int KS = 2048, HD = 1024;
  __shared__ u16 Qs[64 * 80];
  __shared__ u16 Ks[64 * 80];
  __shared__ u16 Vts[64 * 72];   // [d][t]
  __shared__ u16 Ps[64 * 72];    // [q][t]

  const int qt = blockIdx.x, hh = blockIdx.y, bb = blockIdx.z;
  const int s0 = qt * 64;
  const int tid = threadIdx.x, w = tid >> 6, lane = tid & 63;
  const int mr = lane & 15, ko = (lane >> 4) * 8, rq = (lane >> 4) * 4;
  const int sr = tid >> 3, sc = (tid & 7) * 8;
  const int vrow = tid >> 2, vtc = (tid & 3) * 16;
  const float qsc = 0.022097086912079608f;  // 1/sqrt(2048)
  const int qg = s0 + w * 16 + mr;          // this lane's query row

#pragma unroll
  for (int p = 0; p < 2; ++p) {
    int row = p * 32 + sr;
    uint4 u = *(const uint4*)(QKb + (size_t)(bb * KS + s0 + row) * 2048 + hh * 64 + sc);
    *(uint4*)&Qs[row * 80 + sc] = u;
  }

  f32x4 accO[4];
#pragma unroll
  for (int j = 0; j < 4; ++j) { f32x4 z = {0.f,0.f,0.f,0.f}; accO[j] = z; }
  float lsum = 0.f;

  for (int c = 0; c < 9; ++c) {
    int tb = s0 - 256 + c * 64;
    if (tb < 0 || tb >= KS) continue;
    __syncthreads();
#pragma unroll
    for (int p = 0; p < 2; ++p) {
      int row = p * 32 + sr;
      uint4 uk = *(const uint4*)(QKb + (size_t)(bb * KS + tb + row) * 2048 + 1024 + hh * 64 + sc);
      *(uint4*)&Ks[row * 80 + sc] = uk;
    }
    {
      const u16* vsrc = Vt + (size_t)(hh * 64 + vrow) * 4096 + bb * KS + tb + vtc;
      *(uint4*)&Vts[vrow * 72 + vtc]     = *(const uint4*)vsrc;
      *(uint4*)&Vts[vrow * 72 + vtc + 8] = *(const uint4*)(vsrc + 8);
    }
    __syncthreads();

    f32x4 sacc[4];
#pragma unroll
    for (int j = 0; j < 4; ++j) { f32x4 z = {0.f,0.f,0.f,0.f}; sacc[j] = z; }
#pragma unroll
    for (int s = 0; s < 2; ++s) {
      bf16x8 aq = *(const bf16x8*)&Qs[(w * 16 + mr) * 80 + s * 32 + ko];
#pragma unroll
      for (int j = 0; j < 4; ++j) {
        bf16x8 bk = *(const bf16x8*)&Ks[(j * 16 + mr) * 80 + s * 32 + ko];
        sacc[j] = __builtin_amdgcn_mfma_f32_16x16x32_bf16(bk, aq, sacc[j], 0, 0, 0);
      }
    }

#pragma unroll
    for (int j = 0; j < 4; ++j) {
      int tgb = tb + j * 16 + rq;
      float p0, p1, p2, p3;
      {
        int d0 = qg - tgb;
        float s_ = sacc[j][0] * qsc;
        p0 = (d0 > 256 || d0 < -256) ? 0.f : __expf(s_);
        int d1 = d0 - 1; s_ = sacc[j][1] * qsc;
        p1 = (d1 > 256 || d1 < -256) ? 0.f : __expf(s_);
        int d2 = d0 - 2; s_ = sacc[j][2] * qsc;
        p2 = (d2 > 256 || d2 < -256) ? 0.f : __expf(s_);
        int d3 = d0 - 3; s_ = sacc[j][3] * qsc;
        p3 = (d3 > 256 || d3 < -256) ? 0.f : __expf(s_);
      }
      lsum += p0 + p1 + p2 + p3;
      uint32_t lo = (uint32_t)f2bf(p0) | ((uint32_t)f2bf(p1) << 16);
      uint32_t hi = (uint32_t)f2bf(p2) | ((uint32_t)f2bf(p3) << 16);
      *(uint2*)&Ps[(w * 16 + mr) * 72 + j * 16 + rq] = make_uint2(lo, hi);
    }
#pragma unroll
    for (int s = 0; s < 2; ++s) {
      bf16x8 ap = *(const bf16x8*)&Ps[(w * 16 + mr) * 72 + s * 32 + ko];
#pragma unroll
      for (int j = 0; j < 4; ++j) {
        bf16x8 bv = *(const bf16x8*)&Vts[(j * 16 + mr) * 72 + s * 32 + ko];
        accO[j] = __builtin_amdgcn_mfma_f32_16x16x32_bf16(bv, ap, accO[j], 0, 0, 0);
      }
    }
  }

  float l = lsum;
  l += __shfl_xor(l, 16, 64);
  l += __shfl_xor(l, 32, 64);
  float inv = 1.f / l;
  size_t base = (size_t)(bb * KS + qg) * HD + hh * 64;
#pragma unroll
  for (int j = 0; j < 4; ++j) {
    uint32_t lo = (uint32_t)f2bf(accO[j][0] * inv) | ((uint32_t)f2bf(accO[j][1] * inv) << 16);
    uint32_t hi = (uint32_t)f2bf(accO[j][2] * inv) | ((uint32_t)f2bf(accO[j][3] * inv) << 16);
    *(uint2*)(ctx + base + j * 16 + rq) = make_uint2(lo, hi);
  }
}

// ---------------------------------------------------------------------------
// LayerNorm(p0 + p1 + res) over D=1024; all inputs bf16.
// ---------------------------------------------------------------------------
DEVI void bfadd4(const u16* p, size_t base, float& v0, float& v1, float& v2, float& v3) {
  uint2 u = *(const uint2*)(p + base);
  v0 += bf2f((u16)(u.x & 0xFFFFu));
  v1 += bf2f((u16)(u.x >> 16));
  v2 += bf2f((u16)(u.y & 0xFFFFu));
  v3 += bf2f((u16)(u.y >> 16));
}

template<int OUT32>
__global__ __launch_bounds__(256)
void ln_kernel(const u16* __restrict__ p0, const u16* __restrict__ p1,
               const u16* __restrict__ res, const float* __restrict__ g,
               const float* __restrict__ be, void* __restrict__ out)
{
  __shared__ float red[8];
  const int row = blockIdx.x, tid = threadIdx.x;
  const int w = tid >> 6, lane = tid & 63;
  size_t base = (size_t)row * 1024 + tid * 4;
  float v0 = 0.f, v1 = 0.f, v2 = 0.f, v3 = 0.f;
  bfadd4(p0, base, v0, v1, v2, v3);
  bfadd4(p1, base, v0, v1, v2, v3);
  bfadd4(res, base, v0, v1, v2, v3);
  float s1 = v0 + v1 + v2 + v3;
  float s2 = v0 * v0 + v1 * v1 + v2 * v2 + v3 * v3;
#pragma unroll
  for (int o = 32; o > 0; o >>= 1) {
    s1 += __shfl_xor(s1, o, 64);
    s2 += __shfl_xor(s2, o, 64);
  }
  if (lane == 0) { red[w] = s1; red[4 + w] = s2; }
  __syncthreads();
  s1 = red[0] + red[1] + red[2] + red[3];
  s2 = red[4] + red[5] + red[6] + red[7];
  float mu = s1 * (1.f / 1024.f);
  float var = s2 * (1.f / 1024.f) - mu * mu;
  float rs = rsqrtf(var + 1e-5f);
  float4 gv = *(const float4*)(g + tid * 4);
  float4 bv = *(const float4*)(be + tid * 4);
  float o0 = (v0 - mu) * rs * gv.x + bv.x;
  float o1 = (v1 - mu) * rs * gv.y + bv.y;
  float o2 = (v2 - mu) * rs * gv.z + bv.z;
  float o3 = (v3 - mu) * rs * gv.w + bv.w;
  if (OUT32) {
    float4 ov; ov.x = o0; ov.y = o1; ov.z = o2; ov.w = o3;
    *(float4*)((float*)out + base) = ov;
  } else {
    uint32_t lo = (uint32_t)f2bf(o0) | ((uint32_t)f2bf(o1) << 16);
    uint32_t hi = (uint32_t)f2bf(o2) | ((uint32_t)f2bf(o3) << 16);
    *(uint2*)((u16*)out + base) = make_uint2(lo, hi);
  }
}

// ---------------------------------------------------------------------------
// ws layout (64 MiB), MiB offsets, lifetime-verified (unchanged):
//  [0,8)   W1T -> Y0b;  [8,16) xb -> Y1b;  [16,24) WqkvT/WoT -> X1b
//  [24,40) QKb -> SA0b/SA1b -> Hb[lo];  [40,48) Vt -> Hb[mid]
//  [48,56) bqkv -> Cb -> Hb[hi];  [56,64) W2T
// ---------------------------------------------------------------------------
extern "C" void kernel_launch(void* const* d_in, const int* in_sizes, int n_in,
                              void* d_out, int out_size, void* d_ws, size_t ws_size,
                              hipStream_t stream)
{
  (void)in_sizes; (void)n_in; (void)out_size; (void)ws_size;
  const float* x   = (const float*)d_in[0];
  const float* Wq  = (const float*)d_in[1];
  const float* bq  = (const float*)d_in[2];
  const float* Wk  = (const float*)d_in[3];
  const float* bk  = (const float*)d_in[4];
  const float* Wv  = (const float*)d_in[5];
  const float* bv  = (const float*)d_in[6];
  const float* Wo  = (const float*)d_in[7];
  const float* bo  = (const float*)d_in[8];
  const float* W1  = (const float*)d_in[9];
  const float* b1  = (const float*)d_in[10];
  const float* W2  = (const float*)d_in[11];
  const float* b2  = (const float*)d_in[12];
  const float* g1  = (const float*)d_in[13];
  const float* be1 = (const float*)d_in[14];
  const float* g2  = (const float*)d_in[15];
  const float* be2 = (const float*)d_in[16];

  char* ws = (char*)d_ws;
  const size_t MB = 1048576;
  u16*   W1T   = (u16*)(ws + 0 * MB);
  u16*   Y0b   = (u16*)(ws + 0 * MB);
  u16*   xb    = (u16*)(ws + 8 * MB);
  u16*   Y1b   = (u16*)(ws + 8 * MB);
  u16*   WqkvT = (u16*)(ws + 16 * MB);
  u16*   X1b   = (u16*)(ws + 16 * MB);
  u16*   WoT   = (u16*)(ws + 22 * MB);
  u16*   QKb   = (u16*)(ws + 24 * MB);
  u16*   SA0b  = (u16*)(ws + 24 * MB);
  u16*   SA1b  = (u16*)(ws + 32 * MB);
  u16*   Hb    = (u16*)(ws + 24 * MB);
  u16*   Vt    = (u16*)(ws + 40 * MB);
  float* bqkv  = (float*)(ws + 48 * MB);
  u16*   Cb    = (u16*)(ws + 48 * MB);
  u16*   W2T   = (u16*)(ws + 56 * MB);
  float* yout  = (float*)d_out;

  dim3 blk(256);
  dim3 blk512(512);
  // fused prep (one launch)
  prep_kernel<<<7180, blk, 0, stream>>>(Wq, Wk, Wv, Wo, W1, W2, x, bq, bk, bv,
                                        WqkvT, WoT, W1T, W2T, xb, bqkv);
  // G1: fused QKV projection, 256^2 free-run (16x12 = 192 blocks)
  gemm256_kernel<0><<<dim3(192), blk512, 0, stream>>>(xb, WqkvT, bqkv, QKb, Vt, 3072, 1024, 12);
  // attention
  attn_kernel<<<dim3(32, 16, 2), blk, 0, stream>>>(QKb, Vt, Cb);
  // G2: sa = ctx @ Wo + bo, split-K=2 (bf16 partials) — legacy 128^2
  gemm_kernel<2><<<dim3(8, 32, 2), blk, 0, stream>>>(Cb, WoT, bo, SA0b, SA1b, 1024, 1024, 512);
  // LN1: x1 = LN(sa0 + sa1 + xb) -> bf16
  ln_kernel<0><<<4096, blk, 0, stream>>>(SA0b, SA1b, xb, g1, be1, X1b);
  // G3: h = gelu(x1 @ W1 + b1), 256^2 free-run (16x16 = 256 blocks)
  gemm256_kernel<1><<<dim3(256), blk512, 0, stream>>>(X1b, W1T, b1, Hb, nullptr, 4096, 1024, 16);
  // G4: y = h @ W2 + b2, split-K=2 (bf16 partials) — legacy 128^2
  gemm_kernel<2><<<dim3(8, 32, 2), blk, 0, stream>>>(Hb, W2T, b2, Y0b, Y1b, 1024, 4096, 2048);
  // LN2: out = LN(y0 + y1 + x1) -> fp32 d_out
  ln_kernel<1><<<4096, blk, 0, stream>>>(Y0b, Y1b, X1b, g2, be2, yout);
}

// Round 5
// 320.936 us; speedup vs baseline: 1.0579x; 1.0148x over previous
//
#include <hip/hip_runtime.h>
#include <cstdint>
#include <math.h>

typedef unsigned short u16;
typedef __attribute__((ext_vector_type(8))) short bf16x8;  // 8 bf16 (4 VGPRs)
typedef __attribute__((ext_vector_type(4))) float f32x4;   // MFMA acc

#define DEVI __device__ __forceinline__

DEVI u16 f2bf(float f) {
  union { float f; uint32_t u; } v; v.f = f;
  return (u16)((v.u + 0x7FFFu + ((v.u >> 16) & 1u)) >> 16);  // RNE
}
DEVI float bf2f(u16 h) {
  union { uint32_t u; float f; } v; v.u = ((uint32_t)h) << 16;
  return v.f;
}

// async global->LDS, 16B per lane. LDS dst = wave-uniform base + lane*16.
DEVI void gload16(const void* g, void* l) {
  __builtin_amdgcn_global_load_lds(
      (const __attribute__((address_space(1))) void*)g,
      (__attribute__((address_space(3))) void*)l, 16, 0, 0);
}

// tanh-form GELU: u*(1 - 1/(1+e^{2*0.79788456*(u+0.044715u^3)}))
DEVI float gelu_fast(float u) {
  float u2 = u * u;
  float t = __builtin_fmaf(0.044715f * u2, u, u);
  float e = __expf(1.5957691216057308f * t);
  float r = __builtin_amdgcn_rcpf(1.0f + e);
  return u - u * r;
}

// ---------------------------------------------------------------------------
// fp32 W[K][N] -> bf16 Wt[N][K] transpose-convert, one 64x64 tile via LDS
// ---------------------------------------------------------------------------
DEVI void tcvt_body(const float* __restrict__ W, u16* __restrict__ Wt,
                    int Kd, int N, int n0, int k0, float* t) {
  const int r = threadIdx.x >> 4, c4 = (threadIdx.x & 15) * 4;
#pragma unroll
  for (int p = 0; p < 4; ++p) {
    int row = p * 16 + r;
    float4 f = *(const float4*)(W + (size_t)(k0 + row) * N + n0 + c4);
    *(float4*)&t[row * 68 + c4] = f;
  }
  __syncthreads();
#pragma unroll
  for (int p = 0; p < 4; ++p) {
    int n = p * 16 + r;
    float v0 = t[(c4 + 0) * 68 + n];
    float v1 = t[(c4 + 1) * 68 + n];
    float v2 = t[(c4 + 2) * 68 + n];
    float v3 = t[(c4 + 3) * 68 + n];
    uint32_t lo = (uint32_t)f2bf(v0) | ((uint32_t)f2bf(v1) << 16);
    uint32_t hi = (uint32_t)f2bf(v2) | ((uint32_t)f2bf(v3) << 16);
    *(uint2*)(Wt + (size_t)(n0 + n) * Kd + k0 + c4) = make_uint2(lo, hi);
  }
}

// ---------------------------------------------------------------------------
// Fused prep: all weight transpose-converts + x convert + bias concat.
// ---------------------------------------------------------------------------
__global__ __launch_bounds__(256)
void prep_kernel(const float* __restrict__ Wq, const float* __restrict__ Wk,
                 const float* __restrict__ Wv, const float* __restrict__ Wo,
                 const float* __restrict__ W1, const float* __restrict__ W2,
                 const float* __restrict__ x, const float* __restrict__ bq,
                 const float* __restrict__ bk, const float* __restrict__ bv,
                 u16* __restrict__ WqkvT, u16* __restrict__ WoT,
                 u16* __restrict__ W1T, u16* __restrict__ W2T,
                 u16* __restrict__ xb, float* __restrict__ bqkv)
{
  __shared__ float t[64 * 68];
  const int b = blockIdx.x;
  if (b < 1024) {
    int wsel = b >> 8, tt = b & 255;
    const float* W = (wsel == 0) ? Wq : (wsel == 1) ? Wk : (wsel == 2) ? Wv : Wo;
    u16* dst = (wsel == 3) ? WoT : WqkvT + (size_t)wsel * 1024 * 1024;
    tcvt_body(W, dst, 1024, 1024, (tt & 15) * 64, (tt >> 4) * 64, t);
  } else if (b < 2048) {
    int tt = b - 1024;
    tcvt_body(W1, W1T, 1024, 4096, (tt & 63) * 64, (tt >> 6) * 64, t);
  } else if (b < 3072) {
    int tt = b - 2048;
    tcvt_body(W2, W2T, 4096, 1024, (tt & 15) * 64, (tt >> 4) * 64, t);
  } else if (b < 7168) {
    int i = ((b - 3072) * 256 + threadIdx.x) * 4;
    float4 f = *(const float4*)(x + i);
    uint32_t lo = (uint32_t)f2bf(f.x) | ((uint32_t)f2bf(f.y) << 16);
    uint32_t hi = (uint32_t)f2bf(f.z) | ((uint32_t)f2bf(f.w) << 16);
    *(uint2*)(xb + i) = make_uint2(lo, hi);
  } else {
    int i = (b - 7168) * 256 + threadIdx.x;  // 0..3071
    const float* s = (i < 1024) ? bq : ((i < 2048) ? bk : bv);
    bqkv[i] = s[i & 1023];
  }
}

// ---------------------------------------------------------------------------
// Legacy GEMM: 128x128 tile, BK=64, 256 thr. Used for G2/G4 (N=1024 shapes).
// ---------------------------------------------------------------------------
template<int MODE>
__global__ __launch_bounds__(256, 4)
void gemm_kernel(const u16* __restrict__ A, const u16* __restrict__ Bt,
                 const float* __restrict__ bias, void* __restrict__ C0,
                 void* __restrict__ C1, int N, int Kfull, int Kpart)
{
  __shared__ u16 As0[128 * 32], As1[128 * 32];
  __shared__ u16 Bs0[128 * 32], Bs1[128 * 32];
  const int tid = threadIdx.x;
  const int nbx = gridDim.x, nby = gridDim.y;
  int lin = blockIdx.y * nbx + blockIdx.x;
  int band = lin / (8 * nbx);
  int rem = lin - band * (8 * nbx);
  int gsz = min(nby - band * 8, 8);
  const int m0 = (band * 8 + rem % gsz) * 128;
  const int n0 = (rem / gsz) * 128;
  const int kbase = (MODE == 2) ? (int)blockIdx.z * Kpart : 0;
  const int w = tid >> 6, lane = tid & 63;
  const int wm = (w >> 1) * 64, wn = (w & 1) * 64;
  const int mr = lane & 15, ko = (lane >> 4) * 8;
  const int rq = (lane >> 4) * 4;
  const int w32 = w * 32;

  f32x4 acc[4][4];
#pragma unroll
  for (int i = 0; i < 4; ++i)
#pragma unroll
    for (int j = 0; j < 4; ++j) {
      f32x4 z = {0.f, 0.f, 0.f, 0.f};
      acc[i][j] = z;
    }

  const int lr = lane >> 2, lk = (lane & 3) * 8;
  const u16* aG = A  + (size_t)(m0 + w32 + lr) * Kfull + kbase + lk;
  const u16* bG = Bt + (size_t)(n0 + w32 + lr) * Kfull + kbase + lk;
  u16* aD00 = &As0[(w32 +  0) * 32];
  u16* aD01 = &As0[(w32 + 16) * 32];
  u16* aD10 = &As1[(w32 +  0) * 32];
  u16* aD11 = &As1[(w32 + 16) * 32];
  u16* bD00 = &Bs0[(w32 +  0) * 32];
  u16* bD01 = &Bs0[(w32 + 16) * 32];
  u16* bD10 = &Bs1[(w32 +  0) * 32];
  u16* bD11 = &Bs1[(w32 + 16) * 32];
  const size_t row16 = (size_t)16 * Kfull;

  for (int k0 = 0; k0 < Kpart; k0 += 64) {
    gload16(aG + k0,              aD00);
    gload16(aG + row16 + k0,      aD01);
    gload16(aG + k0 + 32,         aD10);
    gload16(aG + row16 + k0 + 32, aD11);
    gload16(bG + k0,              bD00);
    gload16(bG + row16 + k0,      bD01);
    gload16(bG + k0 + 32,         bD10);
    gload16(bG + row16 + k0 + 32, bD11);
    __syncthreads();
#pragma unroll
    for (int s = 0; s < 2; ++s) {
      const u16* Ap = s ? As1 : As0;
      const u16* Bp = s ? Bs1 : Bs0;
      bf16x8 af[4], bf[4];
#pragma unroll
      for (int i = 0; i < 4; ++i)
        af[i] = *(const bf16x8*)&Ap[(wm + i * 16 + mr) * 32 + ko];
#pragma unroll
      for (int j = 0; j < 4; ++j)
        bf[j] = *(const bf16x8*)&Bp[(wn + j * 16 + mr) * 32 + ko];
#pragma unroll
      for (int i = 0; i < 4; ++i)
#pragma unroll
        for (int j = 0; j < 4; ++j)
          acc[i][j] = __builtin_amdgcn_mfma_f32_16x16x32_bf16(bf[j], af[i], acc[i][j], 0, 0, 0);
    }
    __syncthreads();
  }

  {
    const bool part1 = (MODE == 2) && (blockIdx.z == 1);
#pragma unroll
    for (int i = 0; i < 4; ++i) {
      size_t mrow = (size_t)(m0 + wm + i * 16 + mr) * N;
#pragma unroll
      for (int j = 0; j < 4; ++j) {
        int nb = n0 + wn + j * 16 + rq;
        float v0 = acc[i][j][0], v1 = acc[i][j][1];
        float v2 = acc[i][j][2], v3 = acc[i][j][3];
        if (!part1) {
          float4 b4 = *(const float4*)&bias[nb];
          v0 += b4.x; v1 += b4.y; v2 += b4.z; v3 += b4.w;
        }
        if (MODE == 1) {
          v0 = gelu_fast(v0); v1 = gelu_fast(v1);
          v2 = gelu_fast(v2); v3 = gelu_fast(v3);
        }
        uint32_t lo = (uint32_t)f2bf(v0) | ((uint32_t)f2bf(v1) << 16);
        uint32_t hi = (uint32_t)f2bf(v2) | ((uint32_t)f2bf(v3) << 16);
        u16* dst = part1 ? (u16*)C1 : (u16*)C0;
        *(uint2*)(dst + mrow + nb) = make_uint2(lo, hi);
      }
    }
  }
}

// ---------------------------------------------------------------------------
// 256x256 GEMM, free-running tile schedule (2 barriers/K-tile).
// 512 thr = 8 waves (2m x 4n); per-wave C = 128x64 (acc[8][4] f32x4).
// BK=64; LDS = 2 buf x 2 half x [128 rows x 64 u16] per operand = 128 KiB.
//
// R5 change: MM interleaves k0/k1 MFMAs — all 8 k0 (independent accs), then
// all 8 k1. Reuse distance per acc 1 -> 8, hiding MFMA C->C dependency
// latency (the round-4 adjacent dependent pair stalled the wave every 2nd
// MFMA; with 2 waves/SIMD nothing covered it). Bit-exact accumulation order
// per element (k0 before k1) is preserved.
//
// Sync structure unchanged from round 4 (verified ledger, passed):
//   (a) mid-tile:  vmcnt(4) drains B1^t,A1^t  + barrier (publish cur half1)
//   (b) tile-end:  vmcnt(4) drains A0',B0'    + barrier (publish + WAR fence)
// ---------------------------------------------------------------------------
#define VMW4 asm volatile("s_waitcnt vmcnt(4)" ::: "memory")
#define VMW0 asm volatile("s_waitcnt vmcnt(0)" ::: "memory")
#define BAR  __builtin_amdgcn_s_barrier()
#define PRI1 __builtin_amdgcn_s_setprio(1)
#define PRI0 __builtin_amdgcn_s_setprio(0)

DEVI void stage_half(const u16* __restrict__ G, int row0, int Kfull, int tk,
                     u16* lds_half, int w, int srow, int scol) {
  const u16* s = G + (size_t)(row0 + w * 8 + srow) * Kfull + tk + scol;
  u16* d = lds_half + w * 512;                 // wave-uniform dest
  gload16(s, d);                               // rows [0,64) of the half
  gload16(s + ((size_t)Kfull << 6), d + 4096); // rows [64,128)
}

#define LDA(BASE, HALF)                                                       \
  _Pragma("unroll")                                                           \
  for (int i_ = 0; i_ < 4; ++i_) {                                            \
    const u16* p_ = (BASE) + (HALF) * 8192 + (wm * 64 + i_ * 16 + mr) * 64;   \
    aF[i_][0] = *(const bf16x8*)(p_ + c0);                                    \
    aF[i_][1] = *(const bf16x8*)(p_ + c1);                                    \
  }

#define LDB(BASE, HALF, DST)                                                  \
  _Pragma("unroll")                                                           \
  for (int j_ = 0; j_ < 2; ++j_) {                                            \
    const u16* p_ = (BASE) + (HALF) * 8192 + (wn * 32 + j_ * 16 + mr) * 64;   \
    DST[j_][0] = *(const bf16x8*)(p_ + c0);                                   \
    DST[j_][1] = *(const bf16x8*)(p_ + c1);                                   \
  }

// k-interleaved MFMA cluster: 8 independent k0 ops, then 8 k1 ops.
#define MM(MH, NH, BF)                                                        \
  PRI1;                                                                       \
  _Pragma("unroll")                                                           \
  for (int i_ = 0; i_ < 4; ++i_)                                              \
    _Pragma("unroll")                                                         \
    for (int j_ = 0; j_ < 2; ++j_)                                            \
      acc[(MH)*4+i_][(NH)*2+j_] = __builtin_amdgcn_mfma_f32_16x16x32_bf16(    \
          BF[j_][0], aF[i_][0], acc[(MH)*4+i_][(NH)*2+j_], 0, 0, 0);          \
  _Pragma("unroll")                                                           \
  for (int i_ = 0; i_ < 4; ++i_)                                              \
    _Pragma("unroll")                                                         \
    for (int j_ = 0; j_ < 2; ++j_)                                            \
      acc[(MH)*4+i_][(NH)*2+j_] = __builtin_amdgcn_mfma_f32_16x16x32_bf16(    \
          BF[j_][1], aF[i_][1], acc[(MH)*4+i_][(NH)*2+j_], 0, 0, 0);          \
  PRI0;

#define TILE(DO_STAGE, WA, WB) do {                                           \
    const int cur_ = t & 1, nxt_ = cur_ ^ 1;                                  \
    const int k1_ = (t + 1) << 6;                                             \
    const u16* Ac_ = &As[cur_ * 16384];                                       \
    const u16* Bc_ = &Bs[cur_ * 16384];                                       \
    if (DO_STAGE) {                                                           \
      stage_half(A,  m0,       Kfull, k1_, &As[nxt_ * 16384], w, srow, scol); \
      stage_half(Bt, n0,       Kfull, k1_, &Bs[nxt_ * 16384], w, srow, scol); \
    }                                                                         \
    LDA(Ac_, 0);                                                              \
    LDB(Bc_, 0, bF0);                                                         \
    MM(0, 0, bF0);                                                            \
    WA;                                                                       \
    BAR;   /* (a) publish cur half1 */                                        \
    if (DO_STAGE) {                                                           \
      stage_half(Bt, n0 + 128, Kfull, k1_, &Bs[nxt_ * 16384 + 8192], w, srow, scol); \
      stage_half(A,  m0 + 128, Kfull, k1_, &As[nxt_ * 16384 + 8192], w, srow, scol); \
    }                                                                         \
    LDB(Bc_, 1, bF1);                                                         \
    MM(0, 1, bF1);                                                            \
    LDA(Ac_, 1);                                                              \
    MM(1, 1, bF1);                                                            \
    MM(1, 0, bF0);                                                            \
    WB;                                                                       \
    BAR;   /* (b) publish nxt half0 + WAR fence on cur */                     \
  } while (0)

template<int MODE>
__global__ __launch_bounds__(512, 2)
void gemm256_kernel(const u16* __restrict__ A, const u16* __restrict__ Bt,
                    const float* __restrict__ bias, void* __restrict__ C0,
                    void* __restrict__ C1, int N, int Kfull, int NBN)
{
  __shared__ u16 As[32768];   // 2 buf x 2 half x 128x64
  __shared__ u16 Bs[32768];
  const int tid = threadIdx.x;
  const int w = tid >> 6, lane = tid & 63;
  const int wm = w >> 2, wn = w & 3;           // 2 x 4 waves
  const int mr = lane & 15;
  const int rq = (lane >> 4) * 4;

  // XCD-bijective swizzle (gridDim.x % 8 == 0): same-mt runs share an XCD L2.
  const int lin = blockIdx.x;
  const int q = gridDim.x >> 3;
  const int wg = (lin & 7) * q + (lin >> 3);
  const int mt = wg / NBN, nt = wg - mt * NBN;
  const int m0 = mt * 256, n0 = nt * 256;

  // stage-side mapping (linear LDS dest; inverse-swizzled global source)
  const int srow = lane >> 3;                       // 0..7
  const int scol = ((lane & 7) ^ srow) << 3;        // u16 col within 64
  // read-side swizzled k-columns (u16): byte = (ksub*64 + (lane>>4)*16) ^ ((mr&7)<<4)
  const int bl = (lane >> 4) << 4;
  const int sw = (mr & 7) << 4;
  const int c0 = (bl ^ sw) >> 1;
  const int c1 = ((64 + bl) ^ sw) >> 1;

  f32x4 acc[8][4];
#pragma unroll
  for (int i = 0; i < 8; ++i)
#pragma unroll
    for (int j = 0; j < 4; ++j) {
      f32x4 z = {0.f, 0.f, 0.f, 0.f};
      acc[i][j] = z;
    }

  bf16x8 aF[4][2], bF0[2][2], bF1[2][2];

  const int NT = Kfull >> 6;

  // prologue: tile 0, order A0,B0,B1,A1 -> vmcnt(4) = {A0,B0} landed,
  // {B1,A1} outstanding = steady-state entry invariant.
  stage_half(A,  m0,       Kfull, 0, &As[0],    w, srow, scol);
  stage_half(Bt, n0,       Kfull, 0, &Bs[0],    w, srow, scol);
  stage_half(Bt, n0 + 128, Kfull, 0, &Bs[8192], w, srow, scol);
  stage_half(A,  m0 + 128, Kfull, 0, &As[8192], w, srow, scol);
  VMW4;
  BAR;

  int t = 0;
  for (; t < NT - 1; ++t) {
    TILE(1, VMW4, VMW4);
  }
  TILE(0, VMW0, (void)0);

  // epilogue: m = m0 + (mi>>2)*128 + wm*64 + (mi&3)*16 + mr
  //           n = n0 + (ni>>1)*128 + wn*32 + (ni&1)*16 + rq + r
  if (MODE == 0) {
    if (n0 < 2048) {  // Q,K -> QKb [4096][2048], packed along n
#pragma unroll
      for (int mi = 0; mi < 8; ++mi) {
        int mg = m0 + (mi >> 2) * 128 + wm * 64 + (mi & 3) * 16 + mr;
        size_t mrow = (size_t)mg * 2048;
#pragma unroll
        for (int ni = 0; ni < 4; ++ni) {
          int ng = n0 + (ni >> 1) * 128 + wn * 32 + (ni & 1) * 16 + rq;
          float4 b4 = *(const float4*)&bias[ng];
          f32x4 a = acc[mi][ni];
          uint32_t lo = (uint32_t)f2bf(a[0] + b4.x) | ((uint32_t)f2bf(a[1] + b4.y) << 16);
          uint32_t hi = (uint32_t)f2bf(a[2] + b4.z) | ((uint32_t)f2bf(a[3] + b4.w) << 16);
          *(uint2*)((u16*)C0 + mrow + ng) = make_uint2(lo, hi);
        }
      }
    } else {          // V -> Vt [1024][4096] transposed
#pragma unroll
      for (int mi = 0; mi < 8; ++mi) {
        int mg = m0 + (mi >> 2) * 128 + wm * 64 + (mi & 3) * 16 + mr;
#pragma unroll
        for (int ni = 0; ni < 4; ++ni) {
          int ng = n0 + (ni >> 1) * 128 + wn * 32 + (ni & 1) * 16 + rq;
          float4 b4 = *(const float4*)&bias[ng];
          f32x4 a = acc[mi][ni];
          int d = ng - 2048;
          ((u16*)C1)[(size_t)(d + 0) * 4096 + mg] = f2bf(a[0] + b4.x);
          ((u16*)C1)[(size_t)(d + 1) * 4096 + mg] = f2bf(a[1] + b4.y);
          ((u16*)C1)[(size_t)(d + 2) * 4096 + mg] = f2bf(a[2] + b4.z);
          ((u16*)C1)[(size_t)(d + 3) * 4096 + mg] = f2bf(a[3] + b4.w);
        }
      }
    }
  } else {            // MODE 1: bias + GELU -> bf16
#pragma unroll
    for (int mi = 0; mi < 8; ++mi) {
      int mg = m0 + (mi >> 2) * 128 + wm * 64 + (mi & 3) * 16 + mr;
      size_t mrow = (size_t)mg * N;
#pragma unroll
      for (int ni = 0; ni < 4; ++ni) {
        int ng = n0 + (ni >> 1) * 128 + wn * 32 + (ni & 1) * 16 + rq;
        float4 b4 = *(const float4*)&bias[ng];
        f32x4 a = acc[mi][ni];
        float v0 = gelu_fast(a[0] + b4.x), v1 = gelu_fast(a[1] + b4.y);
        float v2 = gelu_fast(a[2] + b4.z), v3 = gelu_fast(a[3] + b4.w);
        uint32_t lo = (uint32_t)f2bf(v0) | ((uint32_t)f2bf(v1) << 16);
        uint32_t hi = (uint32_t)f2bf(v2) | ((uint32_t)f2bf(v3) << 16);
        *(uint2*)((u16*)C0 + mrow + ng) = make_uint2(lo, hi);
      }
    }
  }
}

// ---------------------------------------------------------------------------
// Banded MFMA flash attention, simplified softmax. QK^T swapped -> S[t][q]:
// lane owns ONE q -> packed b64 P-writes, scalar l. PV swapped -> O[d][q].
// ---------------------------------------------------------------------------
__global__ __launch_bounds__(256)
void attn_kernel(const u16* __restrict__ QKb, const u16* __restrict__ Vt,
                 u16* __restrict__ ctx)
{
  const int KS = 2048, HD = 1024;
  __shared__ u16 Qs[64 * 80];
  __shared__ u16 Ks[64 * 80];
  __shared__ u16 Vts[64 * 72];   // [d][t]
  __shared__ u16 Ps[64 * 72];    // [q][t]

  const int qt = blockIdx.x, hh = blockIdx.y, bb = blockIdx.z;
  const int s0 = qt * 64;
  const int tid = threadIdx.x, w = tid >> 6, lane = tid & 63;
  const int mr = lane & 15, ko = (lane >> 4) * 8, rq = (lane >> 4) * 4;
  const int sr = tid >> 3, sc = (tid & 7) * 8;
  const int vrow = tid >> 2, vtc = (tid & 3) * 16;
  const float qsc = 0.022097086912079608f;  // 1/sqrt(2048)
  const int qg = s0 + w * 16 + mr;          // this lane's query row

#pragma unroll
  for (int p = 0; p < 2; ++p) {
    int row = p * 32 + sr;
    uint4 u = *(const uint4*)(QKb + (size_t)(bb * KS + s0 + row) * 2048 + hh * 64 + sc);
    *(uint4*)&Qs[row * 80 + sc] = u;
  }

  f32x4 accO[4];
#pragma unroll
  for (int j = 0; j < 4; ++j) { f32x4 z = {0.f,0.f,0.f,0.f}; accO[j] = z; }
  float lsum = 0.f;

  for (int c = 0; c < 9; ++c) {
    int tb = s0 - 256 + c * 64;
    if (tb < 0 || tb >= KS) continue;
    __syncthreads();
#pragma unroll
    for (int p = 0; p < 2; ++p) {
      int row = p * 32 + sr;
      uint4 uk = *(const uint4*)(QKb + (size_t)(bb * KS + tb + row) * 2048 + 1024 + hh * 64 + sc);
      *(uint4*)&Ks[row * 80 + sc] = uk;
    }
    {
      const u16* vsrc = Vt + (size_t)(hh * 64 + vrow) * 4096 + bb * KS + tb + vtc;
      *(uint4*)&Vts[vrow * 72 + vtc]     = *(const uint4*)vsrc;
      *(uint4*)&Vts[vrow * 72 + vtc + 8] = *(const uint4*)(vsrc + 8);
    }
    __syncthreads();

    f32x4 sacc[4];
#pragma unroll
    for (int j = 0; j < 4; ++j) { f32x4 z = {0.f,0.f,0.f,0.f}; sacc[j] = z; }
#pragma unroll
    for (int s = 0; s < 2; ++s) {
      bf16x8 aq = *(const bf16x8*)&Qs[(w * 16 + mr) * 80 + s * 32 + ko];
#pragma unroll
      for (int j = 0; j < 4; ++j) {
        bf16x8 bk = *(const bf16x8*)&Ks[(j * 16 + mr) * 80 + s * 32 + ko];
        sacc[j] = __builtin_amdgcn_mfma_f32_16x16x32_bf16(bk, aq, sacc[j], 0, 0, 0);
      }
    }

#pragma unroll
    for (int j = 0; j < 4; ++j) {
      int tgb = tb + j * 16 + rq;
      float p0, p1, p2, p3;
      {
        int d0 = qg - tgb;
        float s_ = sacc[j][0] * qsc;
        p0 = (d0 > 256 || d0 < -256) ? 0.f : __expf(s_);
        int d1 = d0 - 1; s_ = sacc[j][1] * qsc;
        p1 = (d1 > 256 || d1 < -256) ? 0.f : __expf(s_);
        int d2 = d0 - 2; s_ = sacc[j][2] * qsc;
        p2 = (d2 > 256 || d2 < -256) ? 0.f : __expf(s_);
        int d3 = d0 - 3; s_ = sacc[j][3] * qsc;
        p3 = (d3 > 256 || d3 < -256) ? 0.f : __expf(s_);
      }
      lsum += p0 + p1 + p2 + p3;
      uint32_t lo = (uint32_t)f2bf(p0) | ((uint32_t)f2bf(p1) << 16);
      uint32_t hi = (uint32_t)f2bf(p2) | ((uint32_t)f2bf(p3) << 16);
      *(uint2*)&Ps[(w * 16 + mr) * 72 + j * 16 + rq] = make_uint2(lo, hi);
    }
#pragma unroll
    for (int s = 0; s < 2; ++s) {
      bf16x8 ap = *(const bf16x8*)&Ps[(w * 16 + mr) * 72 + s * 32 + ko];
#pragma unroll
      for (int j = 0; j < 4; ++j) {
        bf16x8 bv = *(const bf16x8*)&Vts[(j * 16 + mr) * 72 + s * 32 + ko];
        accO[j] = __builtin_amdgcn_mfma_f32_16x16x32_bf16(bv, ap, accO[j], 0, 0, 0);
      }
    }
  }

  float l = lsum;
  l += __shfl_xor(l, 16, 64);
  l += __shfl_xor(l, 32, 64);
  float inv = 1.f / l;
  size_t base = (size_t)(bb * KS + qg) * HD + hh * 64;
#pragma unroll
  for (int j = 0; j < 4; ++j) {
    uint32_t lo = (uint32_t)f2bf(accO[j][0] * inv) | ((uint32_t)f2bf(accO[j][1] * inv) << 16);
    uint32_t hi = (uint32_t)f2bf(accO[j][2] * inv) | ((uint32_t)f2bf(accO[j][3] * inv) << 16);
    *(uint2*)(ctx + base + j * 16 + rq) = make_uint2(lo, hi);
  }
}

// ---------------------------------------------------------------------------
// LayerNorm(p0 + p1 + res) over D=1024; all inputs bf16.
// ---------------------------------------------------------------------------
DEVI void bfadd4(const u16* p, size_t base, float& v0, float& v1, float& v2, float& v3) {
  uint2 u = *(const uint2*)(p + base);
  v0 += bf2f((u16)(u.x & 0xFFFFu));
  v1 += bf2f((u16)(u.x >> 16));
  v2 += bf2f((u16)(u.y & 0xFFFFu));
  v3 += bf2f((u16)(u.y >> 16));
}

template<int OUT32>
__global__ __launch_bounds__(256)
void ln_kernel(const u16* __restrict__ p0, const u16* __restrict__ p1,
               const u16* __restrict__ res, const float* __restrict__ g,
               const float* __restrict__ be, void* __restrict__ out)
{
  __shared__ float red[8];
  const int row = blockIdx.x, tid = threadIdx.x;
  const int w = tid >> 6, lane = tid & 63;
  size_t base = (size_t)row * 1024 + tid * 4;
  float v0 = 0.f, v1 = 0.f, v2 = 0.f, v3 = 0.f;
  bfadd4(p0, base, v0, v1, v2, v3);
  bfadd4(p1, base, v0, v1, v2, v3);
  bfadd4(res, base, v0, v1, v2, v3);
  float s1 = v0 + v1 + v2 + v3;
  float s2 = v0 * v0 + v1 * v1 + v2 * v2 + v3 * v3;
#pragma unroll
  for (int o = 32; o > 0; o >>= 1) {
    s1 += __shfl_xor(s1, o, 64);
    s2 += __shfl_xor(s2, o, 64);
  }
  if (lane == 0) { red[w] = s1; red[4 + w] = s2; }
  __syncthreads();
  s1 = red[0] + red[1] + red[2] + red[3];
  s2 = red[4] + red[5] + red[6] + red[7];
  float mu = s1 * (1.f / 1024.f);
  float var = s2 * (1.f / 1024.f) - mu * mu;
  float rs = rsqrtf(var + 1e-5f);
  float4 gv = *(const float4*)(g + tid * 4);
  float4 bv = *(const float4*)(be + tid * 4);
  float o0 = (v0 - mu) * rs * gv.x + bv.x;
  float o1 = (v1 - mu) * rs * gv.y + bv.y;
  float o2 = (v2 - mu) * rs * gv.z + bv.z;
  float o3 = (v3 - mu) * rs * gv.w + bv.w;
  if (OUT32) {
    float4 ov; ov.x = o0; ov.y = o1; ov.z = o2; ov.w = o3;
    *(float4*)((float*)out + base) = ov;
  } else {
    uint32_t lo = (uint32_t)f2bf(o0) | ((uint32_t)f2bf(o1) << 16);
    uint32_t hi = (uint32_t)f2bf(o2) | ((uint32_t)f2bf(o3) << 16);
    *(uint2*)((u16*)out + base) = make_uint2(lo, hi);
  }
}

// ---------------------------------------------------------------------------
// ws layout (64 MiB), MiB offsets, lifetime-verified (unchanged):
//  [0,8)   W1T -> Y0b;  [8,16) xb -> Y1b;  [16,24) WqkvT/WoT -> X1b
//  [24,40) QKb -> SA0b/SA1b -> Hb[lo];  [40,48) Vt -> Hb[mid]
//  [48,56) bqkv -> Cb -> Hb[hi];  [56,64) W2T
// ---------------------------------------------------------------------------
extern "C" void kernel_launch(void* const* d_in, const int* in_sizes, int n_in,
                              void* d_out, int out_size, void* d_ws, size_t ws_size,
                              hipStream_t stream)
{
  (void)in_sizes; (void)n_in; (void)out_size; (void)ws_size;
  const float* x   = (const float*)d_in[0];
  const float* Wq  = (const float*)d_in[1];
  const float* bq  = (const float*)d_in[2];
  const float* Wk  = (const float*)d_in[3];
  const float* bk  = (const float*)d_in[4];
  const float* Wv  = (const float*)d_in[5];
  const float* bv  = (const float*)d_in[6];
  const float* Wo  = (const float*)d_in[7];
  const float* bo  = (const float*)d_in[8];
  const float* W1  = (const float*)d_in[9];
  const float* b1  = (const float*)d_in[10];
  const float* W2  = (const float*)d_in[11];
  const float* b2  = (const float*)d_in[12];
  const float* g1  = (const float*)d_in[13];
  const float* be1 = (const float*)d_in[14];
  const float* g2  = (const float*)d_in[15];
  const float* be2 = (const float*)d_in[16];

  char* ws = (char*)d_ws;
  const size_t MB = 1048576;
  u16*   W1T   = (u16*)(ws + 0 * MB);
  u16*   Y0b   = (u16*)(ws + 0 * MB);
  u16*   xb    = (u16*)(ws + 8 * MB);
  u16*   Y1b   = (u16*)(ws + 8 * MB);
  u16*   WqkvT = (u16*)(ws + 16 * MB);
  u16*   X1b   = (u16*)(ws + 16 * MB);
  u16*   WoT   = (u16*)(ws + 22 * MB);
  u16*   QKb   = (u16*)(ws + 24 * MB);
  u16*   SA0b  = (u16*)(ws + 24 * MB);
  u16*   SA1b  = (u16*)(ws + 32 * MB);
  u16*   Hb    = (u16*)(ws + 24 * MB);
  u16*   Vt    = (u16*)(ws + 40 * MB);
  float* bqkv  = (float*)(ws + 48 * MB);
  u16*   Cb    = (u16*)(ws + 48 * MB);
  u16*   W2T   = (u16*)(ws + 56 * MB);
  float* yout  = (float*)d_out;

  dim3 blk(256);
  dim3 blk512(512);
  // fused prep (one launch)
  prep_kernel<<<7180, blk, 0, stream>>>(Wq, Wk, Wv, Wo, W1, W2, x, bq, bk, bv,
                                        WqkvT, WoT, W1T, W2T, xb, bqkv);
  // G1: fused QKV projection, 256^2 free-run (16x12 = 192 blocks)
  gemm256_kernel<0><<<dim3(192), blk512, 0, stream>>>(xb, WqkvT, bqkv, QKb, Vt, 3072, 1024, 12);
  // attention
  attn_kernel<<<dim3(32, 16, 2), blk, 0, stream>>>(QKb, Vt, Cb);
  // G2: sa = ctx @ Wo + bo, split-K=2 (bf16 partials) — legacy 128^2
  gemm_kernel<2><<<dim3(8, 32, 2), blk, 0, stream>>>(Cb, WoT, bo, SA0b, SA1b, 1024, 1024, 512);
  // LN1: x1 = LN(sa0 + sa1 + xb) -> bf16
  ln_kernel<0><<<4096, blk, 0, stream>>>(SA0b, SA1b, xb, g1, be1, X1b);
  // G3: h = gelu(x1 @ W1 + b1), 256^2 free-run (16x16 = 256 blocks)
  gemm256_kernel<1><<<dim3(256), blk512, 0, stream>>>(X1b, W1T, b1, Hb, nullptr, 4096, 1024, 16);
  // G4: y = h @ W2 + b2, split-K=2 (bf16 partials) — legacy 128^2
  gemm_kernel<2><<<dim3(8, 32, 2), blk, 0, stream>>>(Hb, W2T, b2, Y0b, Y1b, 1024, 4096, 2048);
  // LN2: out = LN(y0 + y1 + x1) -> fp32 d_out
  ln_kernel<1><<<4096, blk, 0, stream>>>(Y0b, Y1b, X1b, g2, be2, yout);
}